// Round 12
// baseline (267.904 us; speedup 1.0000x reference)
//
#include <hip/hip_runtime.h>
#include <hip/hip_bf16.h>

#define NP 4225      // 65*65 spatial positions
#define PR 2145      // 65*33 rfft bins

typedef __attribute__((ext_vector_type(8))) short short8;    // 8 bf16 (4 VGPRs)
typedef __attribute__((ext_vector_type(4))) float f32x4;
typedef __attribute__((ext_vector_type(4))) unsigned int u32x4;

__device__ inline float bf2f(unsigned short u) {
    union { unsigned int i; float f; } x; x.i = ((unsigned int)u) << 16; return x.f;
}
__device__ inline unsigned short f2bf(float f) {   // RNE
    union { float f; unsigned int i; } x; x.f = f;
    unsigned int r = x.i + 0x7fff + ((x.i >> 16) & 1);
    return (unsigned short)(r >> 16);
}
// relu on 8 packed bf16 (zero halves with sign bit set)
__device__ inline u32x4 relu8(u32x4 v) {
    #pragma unroll
    for (int i = 0; i < 4; i++) {
        unsigned int s = v[i] & 0x80008000u;
        v[i] &= ~((s >> 15) * 0xFFFFu);
    }
    return v;
}
// async global->LDS, 16B per lane; lds base must be wave-uniform
__device__ inline void gl_lds16(const void* g, void* l) {
    __builtin_amdgcn_global_load_lds(
        (const __attribute__((address_space(1))) unsigned int*)g,
        (__attribute__((address_space(3))) unsigned int*)l,
        16, 0, 0);
}
// monotone float->uint encoding for atomicMax (init 0 < enc(any finite float))
__device__ inline unsigned int fenc(float x) {
    unsigned int u = __float_as_uint(x);
    return (u & 0x80000000u) ? ~u : (u | 0x80000000u);
}
__device__ inline float fdec(unsigned int e) {
    return (e & 0x80000000u) ? __uint_as_float(e & 0x7FFFFFFFu) : __uint_as_float(~e);
}

// ---------------- fused projection kernels ----------------

// Computes q[h, dz*32+g] inline, writes qv (bx==0), then qkp partial GEMV.
// Block (1,0,0) also fills the twiddle tables.
__global__ __launch_bounds__(256) void k_qk4(const float* __restrict__ Q,
                                             const float* __restrict__ Wq,
                                             const float* __restrict__ bq,
                                             const float* __restrict__ Wk,
                                             float* __restrict__ qv,
                                             float* __restrict__ qkp,
                                             double* __restrict__ ctd, double* __restrict__ snd,
                                             float* __restrict__ ctf, float* __restrict__ stf)
{
    int bx = blockIdx.x, h = blockIdx.y, dz = blockIdx.z;
    int tid = threadIdx.x;
    if (bx == 1 && h == 0 && dz == 0 && tid < 65) {
        double ang = 6.283185307179586476925286766559 * (double)tid / 65.0;
        double cv = cos(ang), sv = sin(ang);
        ctd[tid] = cv; snd[tid] = sv;
        ctf[tid] = (float)cv; stf[tid] = (float)sv;
    }
    __shared__ float qs[32];
    int g = tid >> 3, l = tid & 7;
    int row = h * 512 + dz * 32 + g;
    float s = 0.f;
    for (int d = l; d < 512; d += 8) s += Q[d] * Wq[(size_t)row * 512 + d];
    s += __shfl_xor(s, 1);
    s += __shfl_xor(s, 2);
    s += __shfl_xor(s, 4);
    if (l == 0) qs[g] = s + bq[row];
    __syncthreads();
    if (bx == 0 && tid < 32) qv[h * 512 + dz * 32 + tid] = qs[tid];
    int c = bx * 256 + tid;
    float s2 = 0.f;
    #pragma unroll 8
    for (int d = 0; d < 32; d++)
        s2 += qs[d] * Wk[(size_t)(h * 512 + dz * 32 + d) * 512 + c];
    qkp[(dz * 8 + h) * 512 + c] = s2;
}

// Ap[cz][h][p] partials: sum over 16 c of qk[h,c]*K[c,p]
__global__ __launch_bounds__(256) void k_alogits3(const float* __restrict__ qkp,
                                                  const float* __restrict__ K,
                                                  float* __restrict__ Ap)
{
    __shared__ float sqk[8][16];
    int tid = threadIdx.x;
    int cz = blockIdx.y;
    if (tid < 128) {
        int hh = tid >> 4, cc = tid & 15;
        float s = 0.f;
        #pragma unroll
        for (int dz = 0; dz < 16; dz++) s += qkp[(dz * 8 + hh) * 512 + cz * 16 + cc];
        sqk[hh][cc] = s;
    }
    __syncthreads();
    int p = blockIdx.x * 256 + tid;
    bool ok = p < NP;
    float acc[8] = {};
    #pragma unroll
    for (int cc = 0; cc < 16; cc++) {
        float kv = ok ? K[(size_t)(cz * 16 + cc) * NP + p] : 0.f;
        #pragma unroll
        for (int h = 0; h < 8; h++) acc[h] += sqk[h][cc] * kv;
    }
    if (ok) {
        #pragma unroll
        for (int h = 0; h < 8; h++) Ap[(size_t)(cz * 8 + h) * NP + p] = acc[h];
    }
}

// Fused: A-row reduce (Ap partials + qb inline) + f64 row-DFT -> TrG/TiG.
__global__ __launch_bounds__(128) void k_ared_fftA(const float* __restrict__ Ap,
                                                   const float* __restrict__ qv,
                                                   const float* __restrict__ bk,
                                                   const double* __restrict__ ctd,
                                                   const double* __restrict__ snd,
                                                   float* __restrict__ TrG, float* __restrict__ TiG)
{
    int y = blockIdx.x, h = blockIdx.y;
    int t = threadIdx.x;
    __shared__ float rowA[65];
    __shared__ double c65[65], s65[65];
    __shared__ float qbred[128];
    float qp = 0.f;
    for (int d = t; d < 512; d += 128) qp += qv[h * 512 + d] * bk[h * 512 + d];
    qbred[t] = qp;
    __syncthreads();
    for (int s = 64; s; s >>= 1) {
        if (t < s) qbred[t] += qbred[t + s];
        __syncthreads();
    }
    float qbh = qbred[0];
    if (t < 65) { c65[t] = ctd[t]; s65[t] = snd[t]; }
    const float sc = 0.04419417382415922f;   // 1/sqrt(512)
    if (t < 65) {
        int p = y * 65 + t;
        float s = 0.f;
        #pragma unroll 8
        for (int cz = 0; cz < 32; cz++) s += Ap[(size_t)(cz * 8 + h) * NP + p];
        rowA[t] = (s + qbh) * sc;
    }
    __syncthreads();
    int v = t;
    if (v < 33) {
        double sr = 0.0, si = 0.0;
        for (int x = 0; x < 65; x++) {
            int m = (v * x) % 65;
            double a = (double)rowA[x];
            sr += a * c65[m];
            si -= a * s65[m];
        }
        TrG[(h * 65 + y) * 33 + v] = (float)sr;
        TiG[(h * 65 + y) * 33 + v] = (float)si;
    }
}

// ---------------- weight prep (merged; both branches; pre-swizzled) ----------------
// Within each 64-elem kc-chunk, element c goes to (c&63)^((m&7)<<3).

__global__ __launch_bounds__(256) void k_wprep(const float* __restrict__ a1,
                                               const float* __restrict__ p1,
                                               const float* __restrict__ a2,
                                               const float* __restrict__ p2,
                                               unsigned short* __restrict__ w1b2,
                                               unsigned short* __restrict__ w2b2)
{
    int i = blockIdx.x * 256 + threadIdx.x;   // < 262144, i = m*512 + c
    int br = blockIdx.y;
    int m = i >> 9, c = i & 511;
    int cs = (c & ~63) | ((c & 63) ^ ((m & 7) << 3));
    if (blockIdx.z == 0) {
        const float* src = br ? p1 : a1;
        w1b2[(size_t)br * 262144 + m * 512 + cs] = f2bf(src[i]);
    } else {
        const float* src = (br ? p2 : a2) + (size_t)i * 9;
        unsigned short* dst = w2b2 + (size_t)br * 512 * 4608;
        #pragma unroll
        for (int t = 0; t < 9; t++) dst[(size_t)m * 4608 + t * 512 + cs] = f2bf(src[t]);
    }
}

// ---------------- MFMA conv kernels ----------------

// conv1x1 (frozen R8 structure): A = K^T, B = w1b[br]. Writes raw bf16 f0b[br].
__global__ __launch_bounds__(256) void k_conv1T(const float* __restrict__ K,
                                                const unsigned short* __restrict__ w1b2,
                                                unsigned short* __restrict__ f0b2)
{
    __shared__ unsigned short As[2][64 * 64];
    __shared__ unsigned short Bs[2][128 * 64];
    int tid = threadIdx.x;
    int bid = blockIdx.x;
    int u = bid & 7;
    int t = bid >> 3;                // 0..71
    int bmi = u * 9 + t % 9;
    if (bmi >= 67) return;
    int combo = t / 9;               // 0..7
    int bm = bmi * 64;               // p tile
    int bn = (combo & 3) * 128;      // m tile
    int br = combo >> 2;
    const unsigned short* w1 = w1b2 + (size_t)br * 262144;
    unsigned short* f0 = f0b2 + (size_t)br * NP * 512;
    int lane = tid & 63;
    int w = tid >> 6;
    int wp = (w >> 1) * 32, wm = (w & 1) * 64;
    int ct = tid >> 4, p4 = (tid & 15) * 4;   // A staging map

    bool okj[4];
    int colj[4];
    #pragma unroll
    for (int j = 0; j < 4; j++) {
        okj[j] = (bm + p4 + j) < NP;
        colj[j] = okj[j] ? (p4 + j) : (NP - 1 - bm);
    }

    f32x4 acc[2][4];
    #pragma unroll
    for (int i = 0; i < 2; i++)
        #pragma unroll
        for (int j = 0; j < 4; j++) acc[i][j] = (f32x4){0.f, 0.f, 0.f, 0.f};

    float aE[16], aO[16];

    auto loadA = [&](int kc, float (&ar)[16]) {
        int c0 = kc * 64;
        #pragma unroll
        for (int pass = 0; pass < 4; pass++) {
            int cl = pass * 16 + ct;
            const float* src = K + (size_t)(c0 + cl) * NP + bm;
            #pragma unroll
            for (int j = 0; j < 4; j++) ar[pass * 4 + j] = src[colj[j]];
        }
    };
    auto writeA = [&](int buf, float (&ar)[16]) {
        #pragma unroll
        for (int pass = 0; pass < 4; pass++) {
            int cl = pass * 16 + ct;
            #pragma unroll
            for (int j = 0; j < 4; j++) {
                int row = p4 + j;
                int byte = (row * 128 + cl * 2) ^ ((row & 7) << 4);
                float v = okj[j] ? ar[pass * 4 + j] : 0.f;
                *(unsigned short*)((char*)As[buf] + byte) = f2bf(v);
            }
        }
    };
    auto stageB = [&](int kc, int buf) {
        const unsigned short* gb = w1 + (size_t)kc * 64 + (lane & 7) * 8;
        #pragma unroll
        for (int j = 0; j < 4; j++) {
            int row = (w * 4 + j) * 8 + (lane >> 3);
            gl_lds16(gb + (size_t)(bn + row) * 512,
                     (char*)Bs[buf] + (w * 4 + j) * 1024);
        }
    };
    auto mfmaStep = [&](int buf) {
        __builtin_amdgcn_s_setprio(1);
        #pragma unroll
        for (int ks = 0; ks < 2; ks++) {
            short8 af[2], bfr[4];
            #pragma unroll
            for (int fi = 0; fi < 2; fi++) {
                int row = wp + fi * 16 + (lane & 15);
                int byte = row * 128 + ((ks * 64 + ((lane >> 4) * 16)) ^ ((row & 7) << 4));
                af[fi] = *(const short8*)((char*)As[buf] + byte);
            }
            #pragma unroll
            for (int fj = 0; fj < 4; fj++) {
                int n = wm + fj * 16 + (lane & 15);
                int byte = n * 128 + ((ks * 64 + ((lane >> 4) * 16)) ^ ((n & 7) << 4));
                bfr[fj] = *(const short8*)((char*)Bs[buf] + byte);
            }
            #pragma unroll
            for (int fi = 0; fi < 2; fi++)
                #pragma unroll
                for (int fj = 0; fj < 4; fj++)
                    acc[fi][fj] = __builtin_amdgcn_mfma_f32_16x16x32_bf16(af[fi], bfr[fj], acc[fi][fj], 0, 0, 0);
        }
        __builtin_amdgcn_s_setprio(0);
    };

    loadA(0, aE);
    loadA(1, aO);
    stageB(0, 0);
    writeA(0, aE);
    __syncthreads();
    #pragma unroll
    for (int ib = 0; ib < 4; ib++) {
        int s0 = 2 * ib;
        if (s0 + 1 < 8) stageB(s0 + 1, 1);
        if (s0 + 2 < 8) loadA(s0 + 2, aE);
        mfmaStep(0);
        if (s0 + 1 < 8) writeA(1, aO);
        __syncthreads();
        int s1 = s0 + 1;
        if (s1 + 1 < 8) stageB(s1 + 1, 0);
        if (s1 + 2 < 8) loadA(s1 + 2, aO);
        mfmaStep(1);
        if (s1 + 1 < 8) writeA(0, aE);
        __syncthreads();
    }
    #pragma unroll
    for (int fi = 0; fi < 2; fi++)
        #pragma unroll
        for (int r = 0; r < 4; r++) {
            int p = bm + wp + fi * 16 + (lane >> 4) * 4 + r;
            if (p >= NP) continue;
            #pragma unroll
            for (int fj = 0; fj < 4; fj++) {
                int m = bn + wm + fj * 16 + (lane & 15);
                f0[(size_t)p * 512 + m] = f2bf(acc[fi][fj][r]);
            }
        }
}

// conv3x3 + residual + relu + fused conv8 partial (atomicAdd into pre-zeroed F2).
// p-tile 128: wave-tile 64x64, acc[4][4], 32 MFMA/step/wave; B-staging traffic halved.
__global__ __launch_bounds__(256) void k_conv3T(const unsigned short* __restrict__ f0b2,
                                                const unsigned short* __restrict__ w2b2,
                                                const float* __restrict__ amp3,
                                                const float* __restrict__ pha3,
                                                float* __restrict__ F2)
{
    __shared__ unsigned short As[2][128 * 64];   // 32 KB
    __shared__ unsigned short Bs[2][128 * 64];   // 32 KB
    __shared__ float w3s[8 * 128];
    int tid = threadIdx.x;
    // decode: XCD u owns one (bn,br) combo for all bm (B panel L2-resident)
    int bid = blockIdx.x;
    int u = bid & 7;
    int bmi = bid >> 3;              // 0..33
    if (bmi >= 34) return;
    int bm = bmi * 128;
    int bnq = u & 3;
    int bn = bnq * 128;
    int br = u >> 2;
    const unsigned short* f0 = f0b2 + (size_t)br * NP * 512;
    const unsigned short* w2 = w2b2 + (size_t)br * 512 * 4608;
    const float* w3 = br ? pha3 : amp3;
    for (int i = tid; i < 1024; i += 256) {
        int h = i >> 7, c = i & 127;
        w3s[i] = w3[h * 512 + bn + c];
    }
    int lane = tid & 63;
    int w = tid >> 6;
    int wp = (w >> 1) * 64, wm = (w & 1) * 64;
    int ra = tid >> 1, sa = tid & 1;   // A staging: 128 rows, 2x 32-elem segments
    int pA = bm + ra;
    int py = pA / 65, px = pA - py * 65;

    f32x4 acc[4][4];
    #pragma unroll
    for (int i = 0; i < 4; i++)
        #pragma unroll
        for (int j = 0; j < 4; j++) acc[i][j] = (f32x4){0.f, 0.f, 0.f, 0.f};

    u32x4 aE[4], aO[4];
    bool vE, vO;

    auto loadA = [&](int s, u32x4 (&a)[4], bool& vv) {
        int kc = s / 9, tap = s - kc * 9;
        int ky = tap / 3 - 1, kx = tap % 3 - 1;
        int sy = py + ky, sx = px + kx;
        bool valid = (pA < NP) && sy >= 0 && sy < 65 && sx >= 0 && sx < 65;
        int srow = valid ? (pA + ky * 65 + kx) : 0;
        const unsigned short* arow = f0 + (size_t)srow * 512 + kc * 64 + sa * 32;
        #pragma unroll
        for (int j = 0; j < 4; j++) a[j] = *(const u32x4*)(arow + j * 8);
        vv = valid;
    };
    auto writeA = [&](int buf, u32x4 (&a)[4], bool vv) {
        u32x4 z = {0, 0, 0, 0};
        int ab = ra * 128 + sa * 64;
        int swz = (ra & 7) << 4;
        #pragma unroll
        for (int j = 0; j < 4; j++) {
            u32x4 wv = vv ? relu8(a[j]) : z;
            *(u32x4*)((char*)As[buf] + ((ab + j * 16) ^ swz)) = wv;
        }
    };
    auto stageB = [&](int s, int buf) {
        int kc = s / 9, tap = s - kc * 9;
        const unsigned short* gb = w2 + (size_t)tap * 512 + kc * 64 + (lane & 7) * 8;
        #pragma unroll
        for (int j = 0; j < 4; j++) {
            int row = (w * 4 + j) * 8 + (lane >> 3);
            gl_lds16(gb + (size_t)(bn + row) * 4608,
                     (char*)Bs[buf] + (w * 4 + j) * 1024);
        }
    };
    auto mfmaStep = [&](int buf) {
        __builtin_amdgcn_s_setprio(1);
        #pragma unroll
        for (int ks = 0; ks < 2; ks++) {
            short8 af[4], bfr[4];
            #pragma unroll
            for (int fi = 0; fi < 4; fi++) {
                int row = wp + fi * 16 + (lane & 15);
                int byte = row * 128 + ((ks * 64 + ((lane >> 4) * 16)) ^ ((row & 7) << 4));
                af[fi] = *(const short8*)((char*)As[buf] + byte);
            }
            #pragma unroll
            for (int fj = 0; fj < 4; fj++) {
                int n = wm + fj * 16 + (lane & 15);
                int byte = n * 128 + ((ks * 64 + ((lane >> 4) * 16)) ^ ((n & 7) << 4));
                bfr[fj] = *(const short8*)((char*)Bs[buf] + byte);
            }
            #pragma unroll
            for (int fi = 0; fi < 4; fi++)
                #pragma unroll
                for (int fj = 0; fj < 4; fj++)
                    acc[fi][fj] = __builtin_amdgcn_mfma_f32_16x16x32_bf16(af[fi], bfr[fj], acc[fi][fj], 0, 0, 0);
        }
        __builtin_amdgcn_s_setprio(0);
    };

    loadA(0, aE, vE);
    loadA(1, aO, vO);
    stageB(0, 0);
    writeA(0, aE, vE);
    __syncthreads();
    for (int ib = 0; ib < 36; ib++) {
        int s0 = 2 * ib;
        if (s0 + 1 < 72) stageB(s0 + 1, 1);
        if (s0 + 2 < 72) loadA(s0 + 2, aE, vE);
        mfmaStep(0);
        if (s0 + 1 < 72) writeA(1, aO, vO);
        __syncthreads();
        int s1 = s0 + 1;
        if (s1 + 1 < 72) stageB(s1 + 1, 0);
        if (s1 + 2 < 72) loadA(s1 + 2, aO, vO);
        mfmaStep(1);
        if (s1 + 1 < 72) writeA(0, aE, vE);
        __syncthreads();
    }
    // epilogue: v = relu(acc + residual) -> LDS (128x128 bf16 tile across As[0..1], swizzled)
    #pragma unroll
    for (int fi = 0; fi < 4; fi++)
        #pragma unroll
        for (int r = 0; r < 4; r++) {
            int row = wp + fi * 16 + (lane >> 4) * 4 + r;
            int p = bm + row;
            #pragma unroll
            for (int fj = 0; fj < 4; fj++) {
                int mcol = wm + fj * 16 + (lane & 15);
                float v = 0.f;
                if (p < NP)
                    v = fmaxf(acc[fi][fj][r] + bf2f(f0[(size_t)p * 512 + bn + mcol]), 0.f);
                int byte = (row * 256 + mcol * 2) ^ ((row & 7) << 4);
                *(unsigned short*)((char*)As + byte) = f2bf(v);
            }
        }
    __syncthreads();
    // fused conv8: partial F2 over this block's 128 channels -> atomicAdd into F2
    int pl = tid >> 1, qc = tid & 1;
    float a8[8] = {};
    #pragma unroll 4
    for (int jj = 0; jj < 32; jj++) {
        int c = qc * 64 + jj * 2;
        int byte = (pl * 256 + c * 2) ^ ((pl & 7) << 4);
        unsigned int uu = *(const unsigned int*)((char*)As + byte);
        float v0 = bf2f((unsigned short)(uu & 0xFFFF));
        float v1 = bf2f((unsigned short)(uu >> 16));
        #pragma unroll
        for (int h = 0; h < 8; h++)
            a8[h] += w3s[h * 128 + c] * v0 + w3s[h * 128 + c + 1] * v1;
    }
    #pragma unroll
    for (int h = 0; h < 8; h++) a8[h] += __shfl_xor(a8[h], 1);
    int p = bm + pl;
    if (qc == 0 && p < NP) {
        #pragma unroll
        for (int h = 0; h < 8; h++)
            atomicAdd(&F2[(size_t)(br * 8 + h) * NP + p], a8[h]);
    }
}

// down-proj both branches: Fo[h][j] = sum_p relu(F2[br][h][p]) * Wd[j][p] + bd[j]
__global__ __launch_bounds__(256) void k_down(const float* __restrict__ F2,
                                              const float* __restrict__ Wd1,
                                              const float* __restrict__ bd1,
                                              const float* __restrict__ Wd2,
                                              const float* __restrict__ bd2,
                                              float* __restrict__ Fa,
                                              float* __restrict__ Fp)
{
    int wid = threadIdx.x >> 6, lane = threadIdx.x & 63;
    int j = blockIdx.x * 4 + wid;
    if (j >= PR) return;
    int br = blockIdx.y;
    const float* Wd = br ? Wd2 : Wd1;
    const float* bd = br ? bd2 : bd1;
    const float* F2b = F2 + (size_t)br * 8 * NP;
    float* Fo = br ? Fp : Fa;
    const float* wr = Wd + (size_t)j * NP;
    float acc[8] = {};
    for (int p = lane; p < NP; p += 64) {
        float wv = wr[p];
        #pragma unroll
        for (int h = 0; h < 8; h++) acc[h] += wv * fmaxf(F2b[h * NP + p], 0.f);
    }
    #pragma unroll
    for (int h = 0; h < 8; h++) {
        #pragma unroll
        for (int off = 32; off; off >>= 1) acc[h] += __shfl_down(acc[h], off);
    }
    if (lane == 0) {
        float b = bd[j];
        #pragma unroll
        for (int h = 0; h < 8; h++) Fo[h * PR + j] = acc[h] + b;
    }
}

// ---------------- FFT stages ----------------

// stage B+C fused: col-DFT (f64) + amp/phase modulation (LDS) + inverse col-DFT (f32)
__global__ __launch_bounds__(128) void k_fftBC(const float* __restrict__ TrG,
                                               const float* __restrict__ TiG,
                                               const float* __restrict__ Fa,
                                               const float* __restrict__ Fp,
                                               const double* __restrict__ ctd,
                                               const double* __restrict__ snd,
                                               const float* __restrict__ ctf,
                                               const float* __restrict__ stf,
                                               float* __restrict__ CrG, float* __restrict__ CiG)
{
    int v = blockIdx.x, h = blockIdx.y;
    int t = threadIdx.x;
    __shared__ float TrS[65], TiS[65];
    __shared__ float BrS[65], BiS[65];
    __shared__ double c65[65], s65[65];
    __shared__ float cf[65], sf[65];
    if (t < 65) {
        TrS[t] = TrG[(h * 65 + t) * 33 + v];
        TiS[t] = TiG[(h * 65 + t) * 33 + v];
        c65[t] = ctd[t]; s65[t] = snd[t];
        cf[t] = ctf[t]; sf[t] = stf[t];
    }
    __syncthreads();
    int uu = t;
    if (uu < 65) {
        double sr = 0.0, si = 0.0;
        for (int y = 0; y < 65; y++) {
            int m = (uu * y) % 65;
            double c = c65[m], s = s65[m];
            double tr = (double)TrS[y], ti = (double)TiS[y];
            sr += tr * c + ti * s;
            si += ti * c - tr * s;
        }
        float re = (float)sr, im = (float)si;
        float mag = sqrtf(re * re + im * im);
        float ang = atan2f(im, re);
        int o = uu * 33 + v;
        float amp = Fa[h * PR + o] * mag;
        float ph  = Fp[h * PR + o] * ang;
        float sn, cn;
        sincosf(ph, &sn, &cn);
        BrS[uu] = amp * cn;
        BiS[uu] = amp * sn;
    }
    __syncthreads();
    int y = t;
    if (y < 65) {
        float sr = 0.f, si = 0.f;
        for (int u2 = 0; u2 < 65; u2++) {
            int m = (u2 * y) % 65;
            float c = cf[m], s = sf[m];
            float ar = BrS[u2], ai = BiS[u2];
            sr += ar * c - ai * s;
            si += ai * c + ar * s;
        }
        CrG[(h * 65 + y) * 33 + v] = sr;
        CiG[(h * 65 + y) * 33 + v] = si;
    }
}

// stage D: irfft rows + fused per-h row-max (atomicMax, uint-encoded)
__global__ __launch_bounds__(128) void k_fftD(const float* __restrict__ CrG,
                                              const float* __restrict__ CiG,
                                              const float* __restrict__ ctf,
                                              const float* __restrict__ stf,
                                              float* __restrict__ A2,
                                              unsigned int* __restrict__ mxb)
{
    int y = blockIdx.x, h = blockIdx.y;
    int t = threadIdx.x;
    __shared__ float CrS[33], CiS[33];
    __shared__ float c65[65], s65[65];
    __shared__ float red[128];
    if (t < 33) {
        CrS[t] = CrG[(h * 65 + y) * 33 + t];
        CiS[t] = CiG[(h * 65 + y) * 33 + t];
    }
    if (t < 65) { c65[t] = ctf[t]; s65[t] = stf[t]; }
    __syncthreads();
    int x = t;
    float s = -3.0e38f;
    if (x < 65) {
        s = CrS[0];
        for (int v = 1; v < 33; v++) {
            int m = (v * x) % 65;
            s += 2.f * (CrS[v] * c65[m] - CiS[v] * s65[m]);
        }
        s *= (1.f / 4225.f);
        A2[h * NP + y * 65 + x] = s;
    }
    red[t] = s;
    __syncthreads();
    for (int st = 64; st; st >>= 1) {
        if (t < st) red[t] = fmaxf(red[t], red[t + st]);
        __syncthreads();
    }
    if (t == 0) atomicMax(&mxb[h], fenc(red[0]));
}

// softmax pass 2: unnormalized weights + per-h sum (atomicAdd into pre-zeroed sumb)
__global__ __launch_bounds__(256) void k_sm2(const float* __restrict__ A2,
                                             const unsigned int* __restrict__ mxb,
                                             float* __restrict__ Wsm,
                                             float* __restrict__ sumb)
{
    int h = blockIdx.y, t = threadIdx.x;
    int p = blockIdx.x * 256 + t;
    float mx = fdec(mxb[h]);
    float w = 0.f;
    if (p < NP) {
        w = expf(A2[h * NP + p] - mx);
        Wsm[h * NP + p] = w;
    }
    __shared__ float red[256];
    red[t] = w;
    __syncthreads();
    for (int st = 128; st; st >>= 1) {
        if (t < st) red[t] += red[t + st];
        __syncthreads();
    }
    if (t == 0) atomicAdd(&sumb[h], red[0]);
}

// t[h][c] += sum_{p in quarter} Wsm_unnorm[h][p] * K[c][p]   (grid (128,4), atomic)
__global__ __launch_bounds__(256) void k_t(const float* __restrict__ K,
                                           const float* __restrict__ Wsm,
                                           float* __restrict__ t)
{
    int wid = threadIdx.x >> 6, lane = threadIdx.x & 63;
    int c = blockIdx.x * 4 + wid;
    int yq = blockIdx.y;
    int p0 = yq * 1057;
    int p1 = p0 + 1057; if (p1 > NP) p1 = NP;
    float acc[8] = {};
    for (int p = p0 + lane; p < p1; p += 64) {
        float kv = K[(size_t)c * NP + p];
        #pragma unroll
        for (int h = 0; h < 8; h++) acc[h] += kv * Wsm[h * NP + p];
    }
    #pragma unroll
    for (int h = 0; h < 8; h++) {
        #pragma unroll
        for (int off = 32; off; off >>= 1) acc[h] += __shfl_down(acc[h], off);
    }
    if (lane == 0) {
        #pragma unroll
        for (int h = 0; h < 8; h++) atomicAdd(&t[h * 512 + c], acc[h]);
    }
}

// x[hd] = (sum_c t[h][c]*Wv[hd][c]) / sumb[h] + bv[hd]
__global__ __launch_bounds__(256) void k_x(const float* __restrict__ t,
                                           const float* __restrict__ sumb,
                                           const float* __restrict__ Wv,
                                           const float* __restrict__ bv,
                                           float* __restrict__ x)
{
    int wid = threadIdx.x >> 6, lane = threadIdx.x & 63;
    int hd = blockIdx.x * 4 + wid;
    int h = hd >> 9;
    float s = 0.f;
    for (int c = lane; c < 512; c += 64) s += t[h * 512 + c] * Wv[(size_t)hd * 512 + c];
    #pragma unroll
    for (int off = 32; off; off >>= 1) s += __shfl_down(s, off);
    if (lane == 0) x[hd] = s / sumb[h] + bv[hd];
}

__global__ __launch_bounds__(256) void k_out(const float* __restrict__ x,
                                             const float* __restrict__ Wo,
                                             const float* __restrict__ bo,
                                             float* __restrict__ out)
{
    int wid = threadIdx.x >> 6, lane = threadIdx.x & 63;
    int j = blockIdx.x * 4 + wid;
    float s = 0.f;
    for (int i = lane; i < 4096; i += 64) s += x[i] * Wo[(size_t)j * 4096 + i];
    #pragma unroll
    for (int off = 32; off; off >>= 1) s += __shfl_down(s, off);
    if (lane == 0) out[j] = s + bo[j];
}

extern "C" void kernel_launch(void* const* d_in, const int* in_sizes, int n_in,
                              void* d_out, int out_size, void* d_ws, size_t ws_size,
                              hipStream_t stream)
{
    (void)in_sizes; (void)n_in; (void)out_size; (void)ws_size;
    const float* Q    = (const float*)d_in[0];
    const float* K    = (const float*)d_in[1];
    const float* Wq   = (const float*)d_in[2];
    const float* bq   = (const float*)d_in[3];
    const float* Wk   = (const float*)d_in[4];
    const float* bk   = (const float*)d_in[5];
    const float* Wv   = (const float*)d_in[6];
    const float* bv   = (const float*)d_in[7];
    const float* Wo   = (const float*)d_in[8];
    const float* bo   = (const float*)d_in[9];
    const float* amp1 = (const float*)d_in[10];
    const float* amp2 = (const float*)d_in[11];
    const float* amp3 = (const float*)d_in[12];
    const float* pha1 = (const float*)d_in[13];
    const float* pha2 = (const float*)d_in[14];
    const float* pha3 = (const float*)d_in[15];
    const float* Wd1  = (const float*)d_in[16];
    const float* bd1  = (const float*)d_in[17];
    const float* Wd2  = (const float*)d_in[18];
    const float* bd2  = (const float*)d_in[19];
    float* out = (float*)d_out;

    char* w = (char*)d_ws;
    auto alloc = [&](size_t bytes) { char* p = w; w += (bytes + 255) & ~(size_t)255; return p; };
    float* qv   = (float*)alloc(4096 * 4);
    float* qkp  = (float*)alloc(16 * 8 * 512 * 4);
    unsigned short* w1b2 = (unsigned short*)alloc((size_t)2 * 512 * 512 * 2);
    unsigned short* w2b2 = (unsigned short*)alloc((size_t)2 * 512 * 4608 * 2);
    unsigned short* f0b2 = (unsigned short*)alloc((size_t)2 * NP * 512 * 2);
    // ---- zeroed region start (single memset) ----
    float* F2   = (float*)alloc((size_t)2 * 8 * NP * 4);
    unsigned int* mxb = (unsigned int*)alloc(8 * 4);
    float* sumb = (float*)alloc(8 * 4);
    float* tt   = (float*)alloc(4096 * 4);
    char* zend  = w;
    // ---- zeroed region end ----
    float* Fa   = (float*)alloc(8 * PR * 4);
    float* Fp   = (float*)alloc(8 * PR * 4);
    double* ctd = (double*)alloc(65 * 8);
    double* snd = (double*)alloc(65 * 8);
    float* ctf  = (float*)alloc(65 * 4);
    float* stf  = (float*)alloc(65 * 4);
    float* TrG  = (float*)alloc(8 * PR * 4);
    float* TiG  = (float*)alloc(8 * PR * 4);
    float* CrG  = (float*)alloc(8 * PR * 4);
    float* CiG  = (float*)alloc(8 * PR * 4);
    // Ap aliases w2b2 (Ap dead before k_wprep writes w2b2)
    float* Ap   = (float*)w2b2;
    // post-conv small buffers alias f0b2 (dead after k_conv3T)
    {
        char* s2 = (char*)f0b2;
        auto alias = [&](size_t bytes) { char* p = s2; s2 += (bytes + 255) & ~(size_t)255; return p; };
        float* A2  = (float*)alias(8 * NP * 4);
        float* wsm = (float*)alias(8 * NP * 4);
        float* xx  = (float*)alias(4096 * 4);

        // zero F2 + mxb + sumb + tt in one shot
        hipMemsetAsync(F2, 0, (size_t)(zend - (char*)F2), stream);

        // attention logits path (fused: q-projection inline, twiddles in one block)
        k_qk4<<<dim3(2, 8, 16), 256, 0, stream>>>(Q, Wq, bq, Wk, qv, qkp, ctd, snd, ctf, stf);
        k_alogits3<<<dim3(17, 32), 256, 0, stream>>>(qkp, K, Ap);
        k_ared_fftA<<<dim3(65, 8), 128, 0, stream>>>(Ap, qv, bk, ctd, snd, TrG, TiG);

        // weight prep (merged, pre-swizzled; overwrites Ap region — after ared_fftA)
        k_wprep<<<dim3(1024, 2, 2), 256, 0, stream>>>(amp1, pha1, amp2, pha2, w1b2, w2b2);

        // conv branches, XCD-pinned 1D grids
        k_conv1T<<<576, 256, 0, stream>>>(K, w1b2, f0b2);
        k_conv3T<<<272, 256, 0, stream>>>(f0b2, w2b2, amp3, pha3, F2);
        k_down<<<dim3(537, 2), 256, 0, stream>>>(F2, Wd1, bd1, Wd2, bd2, Fa, Fp);

        // FFT modulation + softmax + output (f0b2 region reused as scratch)
        k_fftBC<<<dim3(33, 8), 128, 0, stream>>>(TrG, TiG, Fa, Fp, ctd, snd, ctf, stf, CrG, CiG);
        k_fftD<<<dim3(65, 8), 128, 0, stream>>>(CrG, CiG, ctf, stf, A2, mxb);
        k_sm2<<<dim3(17, 8), 256, 0, stream>>>(A2, mxb, wsm, sumb);
        k_t<<<dim3(128, 4), 256, 0, stream>>>(K, wsm, tt);
        k_x<<<1024, 256, 0, stream>>>(tt, sumb, Wv, bv, xx);
        k_out<<<128, 256, 0, stream>>>(xx, Wo, bo, out);
    }
}

// Round 13
// 263.750 us; speedup vs baseline: 1.0157x; 1.0157x over previous
//
#include <hip/hip_runtime.h>
#include <hip/hip_bf16.h>

#define NP 4225      // 65*65 spatial positions
#define PR 2145      // 65*33 rfft bins

typedef __attribute__((ext_vector_type(8))) short short8;    // 8 bf16 (4 VGPRs)
typedef __attribute__((ext_vector_type(4))) float f32x4;
typedef __attribute__((ext_vector_type(4))) unsigned int u32x4;

__device__ inline float bf2f(unsigned short u) {
    union { unsigned int i; float f; } x; x.i = ((unsigned int)u) << 16; return x.f;
}
__device__ inline unsigned short f2bf(float f) {   // RNE
    union { float f; unsigned int i; } x; x.f = f;
    unsigned int r = x.i + 0x7fff + ((x.i >> 16) & 1);
    return (unsigned short)(r >> 16);
}
// relu on 8 packed bf16 (zero halves with sign bit set)
__device__ inline u32x4 relu8(u32x4 v) {
    #pragma unroll
    for (int i = 0; i < 4; i++) {
        unsigned int s = v[i] & 0x80008000u;
        v[i] &= ~((s >> 15) * 0xFFFFu);
    }
    return v;
}
// async global->LDS, 16B per lane; lds base must be wave-uniform
__device__ inline void gl_lds16(const void* g, void* l) {
    __builtin_amdgcn_global_load_lds(
        (const __attribute__((address_space(1))) unsigned int*)g,
        (__attribute__((address_space(3))) unsigned int*)l,
        16, 0, 0);
}
// monotone float->uint encoding for atomicMax (init 0 < enc(any finite float))
__device__ inline unsigned int fenc(float x) {
    unsigned int u = __float_as_uint(x);
    return (u & 0x80000000u) ? ~u : (u | 0x80000000u);
}
__device__ inline float fdec(unsigned int e) {
    return (e & 0x80000000u) ? __uint_as_float(e & 0x7FFFFFFFu) : __uint_as_float(~e);
}

// ---------------- fused projection kernels ----------------

__global__ __launch_bounds__(256) void k_qk4(const float* __restrict__ Q,
                                             const float* __restrict__ Wq,
                                             const float* __restrict__ bq,
                                             const float* __restrict__ Wk,
                                             float* __restrict__ qv,
                                             float* __restrict__ qkp,
                                             double* __restrict__ ctd, double* __restrict__ snd,
                                             float* __restrict__ ctf, float* __restrict__ stf)
{
    int bx = blockIdx.x, h = blockIdx.y, dz = blockIdx.z;
    int tid = threadIdx.x;
    if (bx == 1 && h == 0 && dz == 0 && tid < 65) {
        double ang = 6.283185307179586476925286766559 * (double)tid / 65.0;
        double cv = cos(ang), sv = sin(ang);
        ctd[tid] = cv; snd[tid] = sv;
        ctf[tid] = (float)cv; stf[tid] = (float)sv;
    }
    __shared__ float qs[32];
    int g = tid >> 3, l = tid & 7;
    int row = h * 512 + dz * 32 + g;
    float s = 0.f;
    for (int d = l; d < 512; d += 8) s += Q[d] * Wq[(size_t)row * 512 + d];
    s += __shfl_xor(s, 1);
    s += __shfl_xor(s, 2);
    s += __shfl_xor(s, 4);
    if (l == 0) qs[g] = s + bq[row];
    __syncthreads();
    if (bx == 0 && tid < 32) qv[h * 512 + dz * 32 + tid] = qs[tid];
    int c = bx * 256 + tid;
    float s2 = 0.f;
    #pragma unroll 8
    for (int d = 0; d < 32; d++)
        s2 += qs[d] * Wk[(size_t)(h * 512 + dz * 32 + d) * 512 + c];
    qkp[(dz * 8 + h) * 512 + c] = s2;
}

// Ap[cz][h][p] partials: sum over 16 c of qk[h,c]*K[c,p]
__global__ __launch_bounds__(256) void k_alogits3(const float* __restrict__ qkp,
                                                  const float* __restrict__ K,
                                                  float* __restrict__ Ap)
{
    __shared__ float sqk[8][16];
    int tid = threadIdx.x;
    int cz = blockIdx.y;
    if (tid < 128) {
        int hh = tid >> 4, cc = tid & 15;
        float s = 0.f;
        #pragma unroll
        for (int dz = 0; dz < 16; dz++) s += qkp[(dz * 8 + hh) * 512 + cz * 16 + cc];
        sqk[hh][cc] = s;
    }
    __syncthreads();
    int p = blockIdx.x * 256 + tid;
    bool ok = p < NP;
    float acc[8] = {};
    #pragma unroll
    for (int cc = 0; cc < 16; cc++) {
        float kv = ok ? K[(size_t)(cz * 16 + cc) * NP + p] : 0.f;
        #pragma unroll
        for (int h = 0; h < 8; h++) acc[h] += sqk[h][cc] * kv;
    }
    if (ok) {
        #pragma unroll
        for (int h = 0; h < 8; h++) Ap[(size_t)(cz * 8 + h) * NP + p] = acc[h];
    }
}

// Fused: A-row reduce (Ap partials + qb inline) + f64 row-DFT -> TrG/TiG.
__global__ __launch_bounds__(128) void k_ared_fftA(const float* __restrict__ Ap,
                                                   const float* __restrict__ qv,
                                                   const float* __restrict__ bk,
                                                   const double* __restrict__ ctd,
                                                   const double* __restrict__ snd,
                                                   float* __restrict__ TrG, float* __restrict__ TiG)
{
    int y = blockIdx.x, h = blockIdx.y;
    int t = threadIdx.x;
    __shared__ float rowA[65];
    __shared__ double c65[65], s65[65];
    __shared__ float qbred[128];
    float qp = 0.f;
    for (int d = t; d < 512; d += 128) qp += qv[h * 512 + d] * bk[h * 512 + d];
    qbred[t] = qp;
    __syncthreads();
    for (int s = 64; s; s >>= 1) {
        if (t < s) qbred[t] += qbred[t + s];
        __syncthreads();
    }
    float qbh = qbred[0];
    if (t < 65) { c65[t] = ctd[t]; s65[t] = snd[t]; }
    const float sc = 0.04419417382415922f;   // 1/sqrt(512)
    if (t < 65) {
        int p = y * 65 + t;
        float s = 0.f;
        #pragma unroll 8
        for (int cz = 0; cz < 32; cz++) s += Ap[(size_t)(cz * 8 + h) * NP + p];
        rowA[t] = (s + qbh) * sc;
    }
    __syncthreads();
    int v = t;
    if (v < 33) {
        double sr = 0.0, si = 0.0;
        for (int x = 0; x < 65; x++) {
            int m = (v * x) % 65;
            double a = (double)rowA[x];
            sr += a * c65[m];
            si -= a * s65[m];
        }
        TrG[(h * 65 + y) * 33 + v] = (float)sr;
        TiG[(h * 65 + y) * 33 + v] = (float)si;
    }
}

// ---------------- weight prep (merged; both branches; pre-swizzled) ----------------
// Within each 64-elem kc-chunk, element c goes to (c&63)^((m&7)<<3).

__global__ __launch_bounds__(256) void k_wprep(const float* __restrict__ a1,
                                               const float* __restrict__ p1,
                                               const float* __restrict__ a2,
                                               const float* __restrict__ p2,
                                               unsigned short* __restrict__ w1b2,
                                               unsigned short* __restrict__ w2b2)
{
    int i = blockIdx.x * 256 + threadIdx.x;   // < 262144, i = m*512 + c
    int br = blockIdx.y;
    int m = i >> 9, c = i & 511;
    int cs = (c & ~63) | ((c & 63) ^ ((m & 7) << 3));
    if (blockIdx.z == 0) {
        const float* src = br ? p1 : a1;
        w1b2[(size_t)br * 262144 + m * 512 + cs] = f2bf(src[i]);
    } else {
        const float* src = (br ? p2 : a2) + (size_t)i * 9;
        unsigned short* dst = w2b2 + (size_t)br * 512 * 4608;
        #pragma unroll
        for (int t = 0; t < 9; t++) dst[(size_t)m * 4608 + t * 512 + cs] = f2bf(src[t]);
    }
}

// ---------------- MFMA conv kernels ----------------

// conv1x1 (frozen R8 structure): A = K^T, B = w1b[br]. Writes raw bf16 f0b[br].
__global__ __launch_bounds__(256) void k_conv1T(const float* __restrict__ K,
                                                const unsigned short* __restrict__ w1b2,
                                                unsigned short* __restrict__ f0b2)
{
    __shared__ unsigned short As[2][64 * 64];
    __shared__ unsigned short Bs[2][128 * 64];
    int tid = threadIdx.x;
    int bid = blockIdx.x;
    int u = bid & 7;
    int t = bid >> 3;                // 0..71
    int bmi = u * 9 + t % 9;
    if (bmi >= 67) return;
    int combo = t / 9;               // 0..7
    int bm = bmi * 64;               // p tile
    int bn = (combo & 3) * 128;      // m tile
    int br = combo >> 2;
    const unsigned short* w1 = w1b2 + (size_t)br * 262144;
    unsigned short* f0 = f0b2 + (size_t)br * NP * 512;
    int lane = tid & 63;
    int w = tid >> 6;
    int wp = (w >> 1) * 32, wm = (w & 1) * 64;
    int ct = tid >> 4, p4 = (tid & 15) * 4;   // A staging map

    bool okj[4];
    int colj[4];
    #pragma unroll
    for (int j = 0; j < 4; j++) {
        okj[j] = (bm + p4 + j) < NP;
        colj[j] = okj[j] ? (p4 + j) : (NP - 1 - bm);
    }

    f32x4 acc[2][4];
    #pragma unroll
    for (int i = 0; i < 2; i++)
        #pragma unroll
        for (int j = 0; j < 4; j++) acc[i][j] = (f32x4){0.f, 0.f, 0.f, 0.f};

    float aE[16], aO[16];

    auto loadA = [&](int kc, float (&ar)[16]) {
        int c0 = kc * 64;
        #pragma unroll
        for (int pass = 0; pass < 4; pass++) {
            int cl = pass * 16 + ct;
            const float* src = K + (size_t)(c0 + cl) * NP + bm;
            #pragma unroll
            for (int j = 0; j < 4; j++) ar[pass * 4 + j] = src[colj[j]];
        }
    };
    auto writeA = [&](int buf, float (&ar)[16]) {
        #pragma unroll
        for (int pass = 0; pass < 4; pass++) {
            int cl = pass * 16 + ct;
            #pragma unroll
            for (int j = 0; j < 4; j++) {
                int row = p4 + j;
                int byte = (row * 128 + cl * 2) ^ ((row & 7) << 4);
                float v = okj[j] ? ar[pass * 4 + j] : 0.f;
                *(unsigned short*)((char*)As[buf] + byte) = f2bf(v);
            }
        }
    };
    auto stageB = [&](int kc, int buf) {
        const unsigned short* gb = w1 + (size_t)kc * 64 + (lane & 7) * 8;
        #pragma unroll
        for (int j = 0; j < 4; j++) {
            int row = (w * 4 + j) * 8 + (lane >> 3);
            gl_lds16(gb + (size_t)(bn + row) * 512,
                     (char*)Bs[buf] + (w * 4 + j) * 1024);
        }
    };
    auto mfmaStep = [&](int buf) {
        __builtin_amdgcn_s_setprio(1);
        #pragma unroll
        for (int ks = 0; ks < 2; ks++) {
            short8 af[2], bfr[4];
            #pragma unroll
            for (int fi = 0; fi < 2; fi++) {
                int row = wp + fi * 16 + (lane & 15);
                int byte = row * 128 + ((ks * 64 + ((lane >> 4) * 16)) ^ ((row & 7) << 4));
                af[fi] = *(const short8*)((char*)As[buf] + byte);
            }
            #pragma unroll
            for (int fj = 0; fj < 4; fj++) {
                int n = wm + fj * 16 + (lane & 15);
                int byte = n * 128 + ((ks * 64 + ((lane >> 4) * 16)) ^ ((n & 7) << 4));
                bfr[fj] = *(const short8*)((char*)Bs[buf] + byte);
            }
            #pragma unroll
            for (int fi = 0; fi < 2; fi++)
                #pragma unroll
                for (int fj = 0; fj < 4; fj++)
                    acc[fi][fj] = __builtin_amdgcn_mfma_f32_16x16x32_bf16(af[fi], bfr[fj], acc[fi][fj], 0, 0, 0);
        }
        __builtin_amdgcn_s_setprio(0);
    };

    loadA(0, aE);
    loadA(1, aO);
    stageB(0, 0);
    writeA(0, aE);
    __syncthreads();
    #pragma unroll
    for (int ib = 0; ib < 4; ib++) {
        int s0 = 2 * ib;
        if (s0 + 1 < 8) stageB(s0 + 1, 1);
        if (s0 + 2 < 8) loadA(s0 + 2, aE);
        mfmaStep(0);
        if (s0 + 1 < 8) writeA(1, aO);
        __syncthreads();
        int s1 = s0 + 1;
        if (s1 + 1 < 8) stageB(s1 + 1, 0);
        if (s1 + 2 < 8) loadA(s1 + 2, aO);
        mfmaStep(1);
        if (s1 + 1 < 8) writeA(0, aE);
        __syncthreads();
    }
    #pragma unroll
    for (int fi = 0; fi < 2; fi++)
        #pragma unroll
        for (int r = 0; r < 4; r++) {
            int p = bm + wp + fi * 16 + (lane >> 4) * 4 + r;
            if (p >= NP) continue;
            #pragma unroll
            for (int fj = 0; fj < 4; fj++) {
                int m = bn + wm + fj * 16 + (lane & 15);
                f0[(size_t)p * 512 + m] = f2bf(acc[fi][fj][r]);
            }
        }
}

// conv3x3 + residual + relu + fused conv8 partial (atomicAdd into pre-zeroed F2).
// 64x64 tile, 34 KB LDS -> 4 blocks/CU, grid 1072 (134/XCD; XCD owns 2 B-panels).
__global__ __launch_bounds__(256) void k_conv3T(const unsigned short* __restrict__ f0b2,
                                                const unsigned short* __restrict__ w2b2,
                                                const float* __restrict__ amp3,
                                                const float* __restrict__ pha3,
                                                float* __restrict__ F2)
{
    __shared__ unsigned short As[2][64 * 64];   // 16 KB
    __shared__ unsigned short Bs[2][64 * 64];   // 16 KB
    __shared__ float w3s[8 * 64];               // 2 KB
    int tid = threadIdx.x;
    int bid = blockIdx.x;                // 0..1071
    int u = bid & 7;
    int t = bid >> 3;                    // 0..133
    int bmi = t % 67;
    int cq = t / 67;                     // 0..1
    int combo = u * 2 + cq;              // 0..15
    int bm = bmi * 64;
    int bn = (combo & 7) * 64;
    int br = combo >> 3;
    const unsigned short* f0 = f0b2 + (size_t)br * NP * 512;
    const unsigned short* w2 = w2b2 + (size_t)br * 512 * 4608;
    const float* w3 = br ? pha3 : amp3;
    for (int i = tid; i < 512; i += 256) {
        int h = i >> 6, c = i & 63;
        w3s[i] = w3[h * 512 + bn + c];
    }
    int lane = tid & 63;
    int w = tid >> 6;
    int wp = (w >> 1) * 32, wm = (w & 1) * 32;
    int ra = tid >> 2, sa = tid & 3;   // A staging: row, 16-elem segment
    int pA = bm + ra;
    int py = pA / 65, px = pA - py * 65;

    f32x4 acc[2][2];
    #pragma unroll
    for (int i = 0; i < 2; i++)
        #pragma unroll
        for (int j = 0; j < 2; j++) acc[i][j] = (f32x4){0.f, 0.f, 0.f, 0.f};

    u32x4 aE0, aE1, aO0, aO1;
    bool vE, vO;

    auto loadA = [&](int s, u32x4& a0, u32x4& a1, bool& vv) {
        int kc = s / 9, tap = s - kc * 9;
        int ky = tap / 3 - 1, kx = tap % 3 - 1;
        int sy = py + ky, sx = px + kx;
        bool valid = (pA < NP) && sy >= 0 && sy < 65 && sx >= 0 && sx < 65;
        int srow = valid ? (pA + ky * 65 + kx) : 0;
        const unsigned short* arow = f0 + (size_t)srow * 512 + kc * 64 + sa * 16;
        a0 = *(const u32x4*)arow;
        a1 = *(const u32x4*)(arow + 8);
        vv = valid;
    };
    auto writeA = [&](int buf, u32x4 a0, u32x4 a1, bool vv) {
        u32x4 z = {0, 0, 0, 0};
        u32x4 w0 = vv ? relu8(a0) : z;
        u32x4 w1 = vv ? relu8(a1) : z;
        int ab = ra * 128 + sa * 32;
        int swz = (ra & 7) << 4;
        *(u32x4*)((char*)As[buf] + (ab ^ swz)) = w0;
        *(u32x4*)((char*)As[buf] + ((ab + 16) ^ swz)) = w1;
    };
    auto stageB = [&](int s, int buf) {
        int kc = s / 9, tap = s - kc * 9;
        const unsigned short* gb = w2 + (size_t)tap * 512 + kc * 64 + (lane & 7) * 8;
        #pragma unroll
        for (int j = 0; j < 2; j++) {
            int row = w * 16 + j * 8 + (lane >> 3);
            gl_lds16(gb + (size_t)(bn + row) * 4608,
                     (char*)Bs[buf] + (w * 16 + j * 8) * 128);
        }
    };
    auto mfmaStep = [&](int buf) {
        __builtin_amdgcn_s_setprio(1);
        #pragma unroll
        for (int ks = 0; ks < 2; ks++) {
            short8 af[2], bfr[2];
            #pragma unroll
            for (int fi = 0; fi < 2; fi++) {
                int row = wp + fi * 16 + (lane & 15);
                int byte = row * 128 + ((ks * 64 + ((lane >> 4) * 16)) ^ ((row & 7) << 4));
                af[fi] = *(const short8*)((char*)As[buf] + byte);
            }
            #pragma unroll
            for (int fj = 0; fj < 2; fj++) {
                int n = wm + fj * 16 + (lane & 15);
                int byte = n * 128 + ((ks * 64 + ((lane >> 4) * 16)) ^ ((n & 7) << 4));
                bfr[fj] = *(const short8*)((char*)Bs[buf] + byte);
            }
            #pragma unroll
            for (int fi = 0; fi < 2; fi++)
                #pragma unroll
                for (int fj = 0; fj < 2; fj++)
                    acc[fi][fj] = __builtin_amdgcn_mfma_f32_16x16x32_bf16(af[fi], bfr[fj], acc[fi][fj], 0, 0, 0);
        }
        __builtin_amdgcn_s_setprio(0);
    };

    loadA(0, aE0, aE1, vE);
    loadA(1, aO0, aO1, vO);
    stageB(0, 0);
    writeA(0, aE0, aE1, vE);
    __syncthreads();
    for (int ib = 0; ib < 36; ib++) {
        int s0 = 2 * ib;
        if (s0 + 1 < 72) stageB(s0 + 1, 1);
        if (s0 + 2 < 72) loadA(s0 + 2, aE0, aE1, vE);
        mfmaStep(0);
        if (s0 + 1 < 72) writeA(1, aO0, aO1, vO);
        __syncthreads();
        int s1 = s0 + 1;
        if (s1 + 1 < 72) stageB(s1 + 1, 0);
        if (s1 + 2 < 72) loadA(s1 + 2, aO0, aO1, vO);
        mfmaStep(1);
        if (s1 + 1 < 72) writeA(0, aE0, aE1, vE);
        __syncthreads();
    }
    // epilogue: v = relu(acc + residual) -> LDS (swizzled 64x64 bf16 tile in As[0])
    #pragma unroll
    for (int fi = 0; fi < 2; fi++)
        #pragma unroll
        for (int r = 0; r < 4; r++) {
            int row = wp + fi * 16 + (lane >> 4) * 4 + r;
            int p = bm + row;
            #pragma unroll
            for (int fj = 0; fj < 2; fj++) {
                int mcol = wm + fj * 16 + (lane & 15);
                float v = 0.f;
                if (p < NP)
                    v = fmaxf(acc[fi][fj][r] + bf2f(f0[(size_t)p * 512 + bn + mcol]), 0.f);
                int byte = (row * 128 + mcol * 2) ^ ((row & 7) << 4);
                *(unsigned short*)((char*)As[0] + byte) = f2bf(v);
            }
        }
    __syncthreads();
    // fused conv8: partial F2 over this block's 64 channels -> atomicAdd into F2
    int pl = tid >> 2, qc = tid & 3;
    float a8[8] = {};
    #pragma unroll 4
    for (int jj = 0; jj < 8; jj++) {
        int c = qc * 16 + jj * 2;
        int byte = (pl * 128 + c * 2) ^ ((pl & 7) << 4);
        unsigned int uu = *(const unsigned int*)((char*)As[0] + byte);
        float v0 = bf2f((unsigned short)(uu & 0xFFFF));
        float v1 = bf2f((unsigned short)(uu >> 16));
        #pragma unroll
        for (int h = 0; h < 8; h++)
            a8[h] += w3s[h * 64 + c] * v0 + w3s[h * 64 + c + 1] * v1;
    }
    #pragma unroll
    for (int h = 0; h < 8; h++) {
        a8[h] += __shfl_xor(a8[h], 1);
        a8[h] += __shfl_xor(a8[h], 2);
    }
    int p = bm + pl;
    if (qc == 0 && p < NP) {
        #pragma unroll
        for (int h = 0; h < 8; h++)
            atomicAdd(&F2[(size_t)(br * 8 + h) * NP + p], a8[h]);
    }
}

// down-proj both branches: Fo[h][j] = sum_p relu(F2[br][h][p]) * Wd[j][p] + bd[j]
__global__ __launch_bounds__(256) void k_down(const float* __restrict__ F2,
                                              const float* __restrict__ Wd1,
                                              const float* __restrict__ bd1,
                                              const float* __restrict__ Wd2,
                                              const float* __restrict__ bd2,
                                              float* __restrict__ Fa,
                                              float* __restrict__ Fp)
{
    int wid = threadIdx.x >> 6, lane = threadIdx.x & 63;
    int j = blockIdx.x * 4 + wid;
    if (j >= PR) return;
    int br = blockIdx.y;
    const float* Wd = br ? Wd2 : Wd1;
    const float* bd = br ? bd2 : bd1;
    const float* F2b = F2 + (size_t)br * 8 * NP;
    float* Fo = br ? Fp : Fa;
    const float* wr = Wd + (size_t)j * NP;
    float acc[8] = {};
    for (int p = lane; p < NP; p += 64) {
        float wv = wr[p];
        #pragma unroll
        for (int h = 0; h < 8; h++) acc[h] += wv * fmaxf(F2b[h * NP + p], 0.f);
    }
    #pragma unroll
    for (int h = 0; h < 8; h++) {
        #pragma unroll
        for (int off = 32; off; off >>= 1) acc[h] += __shfl_down(acc[h], off);
    }
    if (lane == 0) {
        float b = bd[j];
        #pragma unroll
        for (int h = 0; h < 8; h++) Fo[h * PR + j] = acc[h] + b;
    }
}

// ---------------- FFT stages ----------------

// stage B+C fused: col-DFT (f64) + amp/phase modulation (LDS) + inverse col-DFT (f32)
__global__ __launch_bounds__(128) void k_fftBC(const float* __restrict__ TrG,
                                               const float* __restrict__ TiG,
                                               const float* __restrict__ Fa,
                                               const float* __restrict__ Fp,
                                               const double* __restrict__ ctd,
                                               const double* __restrict__ snd,
                                               const float* __restrict__ ctf,
                                               const float* __restrict__ stf,
                                               float* __restrict__ CrG, float* __restrict__ CiG)
{
    int v = blockIdx.x, h = blockIdx.y;
    int t = threadIdx.x;
    __shared__ float TrS[65], TiS[65];
    __shared__ float BrS[65], BiS[65];
    __shared__ double c65[65], s65[65];
    __shared__ float cf[65], sf[65];
    if (t < 65) {
        TrS[t] = TrG[(h * 65 + t) * 33 + v];
        TiS[t] = TiG[(h * 65 + t) * 33 + v];
        c65[t] = ctd[t]; s65[t] = snd[t];
        cf[t] = ctf[t]; sf[t] = stf[t];
    }
    __syncthreads();
    int uu = t;
    if (uu < 65) {
        double sr = 0.0, si = 0.0;
        for (int y = 0; y < 65; y++) {
            int m = (uu * y) % 65;
            double c = c65[m], s = s65[m];
            double tr = (double)TrS[y], ti = (double)TiS[y];
            sr += tr * c + ti * s;
            si += ti * c - tr * s;
        }
        float re = (float)sr, im = (float)si;
        float mag = sqrtf(re * re + im * im);
        float ang = atan2f(im, re);
        int o = uu * 33 + v;
        float amp = Fa[h * PR + o] * mag;
        float ph  = Fp[h * PR + o] * ang;
        float sn, cn;
        sincosf(ph, &sn, &cn);
        BrS[uu] = amp * cn;
        BiS[uu] = amp * sn;
    }
    __syncthreads();
    int y = t;
    if (y < 65) {
        float sr = 0.f, si = 0.f;
        for (int u2 = 0; u2 < 65; u2++) {
            int m = (u2 * y) % 65;
            float c = cf[m], s = sf[m];
            float ar = BrS[u2], ai = BiS[u2];
            sr += ar * c - ai * s;
            si += ai * c + ar * s;
        }
        CrG[(h * 65 + y) * 33 + v] = sr;
        CiG[(h * 65 + y) * 33 + v] = si;
    }
}

// stage D: irfft rows + fused per-h row-max (atomicMax, uint-encoded)
__global__ __launch_bounds__(128) void k_fftD(const float* __restrict__ CrG,
                                              const float* __restrict__ CiG,
                                              const float* __restrict__ ctf,
                                              const float* __restrict__ stf,
                                              float* __restrict__ A2,
                                              unsigned int* __restrict__ mxb)
{
    int y = blockIdx.x, h = blockIdx.y;
    int t = threadIdx.x;
    __shared__ float CrS[33], CiS[33];
    __shared__ float c65[65], s65[65];
    __shared__ float red[128];
    if (t < 33) {
        CrS[t] = CrG[(h * 65 + y) * 33 + t];
        CiS[t] = CiG[(h * 65 + y) * 33 + t];
    }
    if (t < 65) { c65[t] = ctf[t]; s65[t] = stf[t]; }
    __syncthreads();
    int x = t;
    float s = -3.0e38f;
    if (x < 65) {
        s = CrS[0];
        for (int v = 1; v < 33; v++) {
            int m = (v * x) % 65;
            s += 2.f * (CrS[v] * c65[m] - CiS[v] * s65[m]);
        }
        s *= (1.f / 4225.f);
        A2[h * NP + y * 65 + x] = s;
    }
    red[t] = s;
    __syncthreads();
    for (int st = 64; st; st >>= 1) {
        if (t < st) red[t] = fmaxf(red[t], red[t + st]);
        __syncthreads();
    }
    if (t == 0) atomicMax(&mxb[h], fenc(red[0]));
}

// softmax pass 2: unnormalized weights + per-h sum (atomicAdd into pre-zeroed sumb)
__global__ __launch_bounds__(256) void k_sm2(const float* __restrict__ A2,
                                             const unsigned int* __restrict__ mxb,
                                             float* __restrict__ Wsm,
                                             float* __restrict__ sumb)
{
    int h = blockIdx.y, t = threadIdx.x;
    int p = blockIdx.x * 256 + t;
    float mx = fdec(mxb[h]);
    float w = 0.f;
    if (p < NP) {
        w = expf(A2[h * NP + p] - mx);
        Wsm[h * NP + p] = w;
    }
    __shared__ float red[256];
    red[t] = w;
    __syncthreads();
    for (int st = 128; st; st >>= 1) {
        if (t < st) red[t] += red[t + st];
        __syncthreads();
    }
    if (t == 0) atomicAdd(&sumb[h], red[0]);
}

// t[h][c] += sum_{p in quarter} Wsm_unnorm[h][p] * K[c][p]   (grid (128,4), atomic)
__global__ __launch_bounds__(256) void k_t(const float* __restrict__ K,
                                           const float* __restrict__ Wsm,
                                           float* __restrict__ t)
{
    int wid = threadIdx.x >> 6, lane = threadIdx.x & 63;
    int c = blockIdx.x * 4 + wid;
    int yq = blockIdx.y;
    int p0 = yq * 1057;
    int p1 = p0 + 1057; if (p1 > NP) p1 = NP;
    float acc[8] = {};
    for (int p = p0 + lane; p < p1; p += 64) {
        float kv = K[(size_t)c * NP + p];
        #pragma unroll
        for (int h = 0; h < 8; h++) acc[h] += kv * Wsm[h * NP + p];
    }
    #pragma unroll
    for (int h = 0; h < 8; h++) {
        #pragma unroll
        for (int off = 32; off; off >>= 1) acc[h] += __shfl_down(acc[h], off);
    }
    if (lane == 0) {
        #pragma unroll
        for (int h = 0; h < 8; h++) atomicAdd(&t[h * 512 + c], acc[h]);
    }
}

// x[hd] = (sum_c t[h][c]*Wv[hd][c]) / sumb[h] + bv[hd]
__global__ __launch_bounds__(256) void k_x(const float* __restrict__ t,
                                           const float* __restrict__ sumb,
                                           const float* __restrict__ Wv,
                                           const float* __restrict__ bv,
                                           float* __restrict__ x)
{
    int wid = threadIdx.x >> 6, lane = threadIdx.x & 63;
    int hd = blockIdx.x * 4 + wid;
    int h = hd >> 9;
    float s = 0.f;
    for (int c = lane; c < 512; c += 64) s += t[h * 512 + c] * Wv[(size_t)hd * 512 + c];
    #pragma unroll
    for (int off = 32; off; off >>= 1) s += __shfl_down(s, off);
    if (lane == 0) x[hd] = s / sumb[h] + bv[hd];
}

__global__ __launch_bounds__(256) void k_out(const float* __restrict__ x,
                                             const float* __restrict__ Wo,
                                             const float* __restrict__ bo,
                                             float* __restrict__ out)
{
    int wid = threadIdx.x >> 6, lane = threadIdx.x & 63;
    int j = blockIdx.x * 4 + wid;
    float s = 0.f;
    for (int i = lane; i < 4096; i += 64) s += x[i] * Wo[(size_t)j * 4096 + i];
    #pragma unroll
    for (int off = 32; off; off >>= 1) s += __shfl_down(s, off);
    if (lane == 0) out[j] = s + bo[j];
}

extern "C" void kernel_launch(void* const* d_in, const int* in_sizes, int n_in,
                              void* d_out, int out_size, void* d_ws, size_t ws_size,
                              hipStream_t stream)
{
    (void)in_sizes; (void)n_in; (void)out_size; (void)ws_size;
    const float* Q    = (const float*)d_in[0];
    const float* K    = (const float*)d_in[1];
    const float* Wq   = (const float*)d_in[2];
    const float* bq   = (const float*)d_in[3];
    const float* Wk   = (const float*)d_in[4];
    const float* bk   = (const float*)d_in[5];
    const float* Wv   = (const float*)d_in[6];
    const float* bv   = (const float*)d_in[7];
    const float* Wo   = (const float*)d_in[8];
    const float* bo   = (const float*)d_in[9];
    const float* amp1 = (const float*)d_in[10];
    const float* amp2 = (const float*)d_in[11];
    const float* amp3 = (const float*)d_in[12];
    const float* pha1 = (const float*)d_in[13];
    const float* pha2 = (const float*)d_in[14];
    const float* pha3 = (const float*)d_in[15];
    const float* Wd1  = (const float*)d_in[16];
    const float* bd1  = (const float*)d_in[17];
    const float* Wd2  = (const float*)d_in[18];
    const float* bd2  = (const float*)d_in[19];
    float* out = (float*)d_out;

    char* w = (char*)d_ws;
    auto alloc = [&](size_t bytes) { char* p = w; w += (bytes + 255) & ~(size_t)255; return p; };
    float* qv   = (float*)alloc(4096 * 4);
    float* qkp  = (float*)alloc(16 * 8 * 512 * 4);
    unsigned short* w1b2 = (unsigned short*)alloc((size_t)2 * 512 * 512 * 2);
    unsigned short* w2b2 = (unsigned short*)alloc((size_t)2 * 512 * 4608 * 2);
    unsigned short* f0b2 = (unsigned short*)alloc((size_t)2 * NP * 512 * 2);
    // ---- zeroed region start (single memset) ----
    float* F2   = (float*)alloc((size_t)2 * 8 * NP * 4);
    unsigned int* mxb = (unsigned int*)alloc(8 * 4);
    float* sumb = (float*)alloc(8 * 4);
    float* tt   = (float*)alloc(4096 * 4);
    char* zend  = w;
    // ---- zeroed region end ----
    float* Fa   = (float*)alloc(8 * PR * 4);
    float* Fp   = (float*)alloc(8 * PR * 4);
    double* ctd = (double*)alloc(65 * 8);
    double* snd = (double*)alloc(65 * 8);
    float* ctf  = (float*)alloc(65 * 4);
    float* stf  = (float*)alloc(65 * 4);
    float* TrG  = (float*)alloc(8 * PR * 4);
    float* TiG  = (float*)alloc(8 * PR * 4);
    float* CrG  = (float*)alloc(8 * PR * 4);
    float* CiG  = (float*)alloc(8 * PR * 4);
    // Ap aliases w2b2 (Ap dead before k_wprep writes w2b2)
    float* Ap   = (float*)w2b2;
    // post-conv small buffers alias f0b2 (dead after k_conv3T)
    {
        char* s2 = (char*)f0b2;
        auto alias = [&](size_t bytes) { char* p = s2; s2 += (bytes + 255) & ~(size_t)255; return p; };
        float* A2  = (float*)alias(8 * NP * 4);
        float* wsm = (float*)alias(8 * NP * 4);
        float* xx  = (float*)alias(4096 * 4);

        // zero F2 + mxb + sumb + tt in one shot
        hipMemsetAsync(F2, 0, (size_t)(zend - (char*)F2), stream);

        // attention logits path (fused: q-projection inline, twiddles in one block)
        k_qk4<<<dim3(2, 8, 16), 256, 0, stream>>>(Q, Wq, bq, Wk, qv, qkp, ctd, snd, ctf, stf);
        k_alogits3<<<dim3(17, 32), 256, 0, stream>>>(qkp, K, Ap);
        k_ared_fftA<<<dim3(65, 8), 128, 0, stream>>>(Ap, qv, bk, ctd, snd, TrG, TiG);

        // weight prep (merged, pre-swizzled; overwrites Ap region — after ared_fftA)
        k_wprep<<<dim3(1024, 2, 2), 256, 0, stream>>>(amp1, pha1, amp2, pha2, w1b2, w2b2);

        // conv branches, XCD-pinned 1D grids
        k_conv1T<<<576, 256, 0, stream>>>(K, w1b2, f0b2);
        k_conv3T<<<1072, 256, 0, stream>>>(f0b2, w2b2, amp3, pha3, F2);
        k_down<<<dim3(537, 2), 256, 0, stream>>>(F2, Wd1, bd1, Wd2, bd2, Fa, Fp);

        // FFT modulation + softmax + output (f0b2 region reused as scratch)
        k_fftBC<<<dim3(33, 8), 128, 0, stream>>>(TrG, TiG, Fa, Fp, ctd, snd, ctf, stf, CrG, CiG);
        k_fftD<<<dim3(65, 8), 128, 0, stream>>>(CrG, CiG, ctf, stf, A2, mxb);
        k_sm2<<<dim3(17, 8), 256, 0, stream>>>(A2, mxb, wsm, sumb);
        k_t<<<dim3(128, 4), 256, 0, stream>>>(K, wsm, tt);
        k_x<<<1024, 256, 0, stream>>>(tt, sumb, Wv, bv, xx);
        k_out<<<128, 256, 0, stream>>>(xx, Wo, bo, out);
    }
}

// Round 14
// 243.033 us; speedup vs baseline: 1.1023x; 1.0852x over previous
//
#include <hip/hip_runtime.h>
#include <hip/hip_bf16.h>

#define NP 4225      // 65*65 spatial positions
#define PR 2145      // 65*33 rfft bins

typedef __attribute__((ext_vector_type(8))) short short8;    // 8 bf16 (4 VGPRs)
typedef __attribute__((ext_vector_type(4))) float f32x4;
typedef __attribute__((ext_vector_type(4))) unsigned int u32x4;

__device__ inline float bf2f(unsigned short u) {
    union { unsigned int i; float f; } x; x.i = ((unsigned int)u) << 16; return x.f;
}
__device__ inline unsigned short f2bf(float f) {   // RNE
    union { float f; unsigned int i; } x; x.f = f;
    unsigned int r = x.i + 0x7fff + ((x.i >> 16) & 1);
    return (unsigned short)(r >> 16);
}
// relu on 8 packed bf16 (zero halves with sign bit set)
__device__ inline u32x4 relu8(u32x4 v) {
    #pragma unroll
    for (int i = 0; i < 4; i++) {
        unsigned int s = v[i] & 0x80008000u;
        v[i] &= ~((s >> 15) * 0xFFFFu);
    }
    return v;
}
// async global->LDS, 16B per lane; lds base must be wave-uniform
__device__ inline void gl_lds16(const void* g, void* l) {
    __builtin_amdgcn_global_load_lds(
        (const __attribute__((address_space(1))) unsigned int*)g,
        (__attribute__((address_space(3))) unsigned int*)l,
        16, 0, 0);
}
// monotone float->uint encoding for atomicMax (init 0 < enc(any finite float))
__device__ inline unsigned int fenc(float x) {
    unsigned int u = __float_as_uint(x);
    return (u & 0x80000000u) ? ~u : (u | 0x80000000u);
}
__device__ inline float fdec(unsigned int e) {
    return (e & 0x80000000u) ? __uint_as_float(e & 0x7FFFFFFFu) : __uint_as_float(~e);
}

// ---------------- fused projection kernels ----------------

// Computes q[h, dz*32+g] inline, writes qv (bx==0), then qkp partial GEMV.
// Block (1,0,0) also fills the twiddle tables.
__global__ __launch_bounds__(256) void k_qk4(const float* __restrict__ Q,
                                             const float* __restrict__ Wq,
                                             const float* __restrict__ bq,
                                             const float* __restrict__ Wk,
                                             float* __restrict__ qv,
                                             float* __restrict__ qkp,
                                             double* __restrict__ ctd, double* __restrict__ snd,
                                             float* __restrict__ ctf, float* __restrict__ stf)
{
    int bx = blockIdx.x, h = blockIdx.y, dz = blockIdx.z;
    int tid = threadIdx.x;
    if (bx == 1 && h == 0 && dz == 0 && tid < 65) {
        double ang = 6.283185307179586476925286766559 * (double)tid / 65.0;
        double cv = cos(ang), sv = sin(ang);
        ctd[tid] = cv; snd[tid] = sv;
        ctf[tid] = (float)cv; stf[tid] = (float)sv;
    }
    __shared__ float qs[32];
    int g = tid >> 3, l = tid & 7;
    int row = h * 512 + dz * 32 + g;
    float s = 0.f;
    for (int d = l; d < 512; d += 8) s += Q[d] * Wq[(size_t)row * 512 + d];
    s += __shfl_xor(s, 1);
    s += __shfl_xor(s, 2);
    s += __shfl_xor(s, 4);
    if (l == 0) qs[g] = s + bq[row];
    __syncthreads();
    if (bx == 0 && tid < 32) qv[h * 512 + dz * 32 + tid] = qs[tid];
    int c = bx * 256 + tid;
    float s2 = 0.f;
    #pragma unroll 8
    for (int d = 0; d < 32; d++)
        s2 += qs[d] * Wk[(size_t)(h * 512 + dz * 32 + d) * 512 + c];
    qkp[(dz * 8 + h) * 512 + c] = s2;
}

// Ap[cz][h][p] partials: sum over 16 c of qk[h,c]*K[c,p]
__global__ __launch_bounds__(256) void k_alogits3(const float* __restrict__ qkp,
                                                  const float* __restrict__ K,
                                                  float* __restrict__ Ap)
{
    __shared__ float sqk[8][16];
    int tid = threadIdx.x;
    int cz = blockIdx.y;
    if (tid < 128) {
        int hh = tid >> 4, cc = tid & 15;
        float s = 0.f;
        #pragma unroll
        for (int dz = 0; dz < 16; dz++) s += qkp[(dz * 8 + hh) * 512 + cz * 16 + cc];
        sqk[hh][cc] = s;
    }
    __syncthreads();
    int p = blockIdx.x * 256 + tid;
    bool ok = p < NP;
    float acc[8] = {};
    #pragma unroll
    for (int cc = 0; cc < 16; cc++) {
        float kv = ok ? K[(size_t)(cz * 16 + cc) * NP + p] : 0.f;
        #pragma unroll
        for (int h = 0; h < 8; h++) acc[h] += sqk[h][cc] * kv;
    }
    if (ok) {
        #pragma unroll
        for (int h = 0; h < 8; h++) Ap[(size_t)(cz * 8 + h) * NP + p] = acc[h];
    }
}

// Fused: A-row reduce (Ap partials + qb inline) + f64 row-DFT -> TrG/TiG.
__global__ __launch_bounds__(128) void k_ared_fftA(const float* __restrict__ Ap,
                                                   const float* __restrict__ qv,
                                                   const float* __restrict__ bk,
                                                   const double* __restrict__ ctd,
                                                   const double* __restrict__ snd,
                                                   float* __restrict__ TrG, float* __restrict__ TiG)
{
    int y = blockIdx.x, h = blockIdx.y;
    int t = threadIdx.x;
    __shared__ float rowA[65];
    __shared__ double c65[65], s65[65];
    __shared__ float qbred[128];
    float qp = 0.f;
    for (int d = t; d < 512; d += 128) qp += qv[h * 512 + d] * bk[h * 512 + d];
    qbred[t] = qp;
    __syncthreads();
    for (int s = 64; s; s >>= 1) {
        if (t < s) qbred[t] += qbred[t + s];
        __syncthreads();
    }
    float qbh = qbred[0];
    if (t < 65) { c65[t] = ctd[t]; s65[t] = snd[t]; }
    const float sc = 0.04419417382415922f;   // 1/sqrt(512)
    if (t < 65) {
        int p = y * 65 + t;
        float s = 0.f;
        #pragma unroll 8
        for (int cz = 0; cz < 32; cz++) s += Ap[(size_t)(cz * 8 + h) * NP + p];
        rowA[t] = (s + qbh) * sc;
    }
    __syncthreads();
    int v = t;
    if (v < 33) {
        double sr = 0.0, si = 0.0;
        for (int x = 0; x < 65; x++) {
            int m = (v * x) % 65;
            double a = (double)rowA[x];
            sr += a * c65[m];
            si -= a * s65[m];
        }
        TrG[(h * 65 + y) * 33 + v] = (float)sr;
        TiG[(h * 65 + y) * 33 + v] = (float)si;
    }
}

// ---------------- weight prep (merged; both branches; pre-swizzled) ----------------
// Within each 64-elem kc-chunk, element c goes to (c&63)^((m&7)<<3).

__global__ __launch_bounds__(256) void k_wprep(const float* __restrict__ a1,
                                               const float* __restrict__ p1,
                                               const float* __restrict__ a2,
                                               const float* __restrict__ p2,
                                               unsigned short* __restrict__ w1b2,
                                               unsigned short* __restrict__ w2b2)
{
    int i = blockIdx.x * 256 + threadIdx.x;   // < 262144, i = m*512 + c
    int br = blockIdx.y;
    int m = i >> 9, c = i & 511;
    int cs = (c & ~63) | ((c & 63) ^ ((m & 7) << 3));
    if (blockIdx.z == 0) {
        const float* src = br ? p1 : a1;
        w1b2[(size_t)br * 262144 + m * 512 + cs] = f2bf(src[i]);
    } else {
        const float* src = (br ? p2 : a2) + (size_t)i * 9;
        unsigned short* dst = w2b2 + (size_t)br * 512 * 4608;
        #pragma unroll
        for (int t = 0; t < 9; t++) dst[(size_t)m * 4608 + t * 512 + cs] = f2bf(src[t]);
    }
}

// ---------------- MFMA conv kernels (R8-proven structure, frozen) ----------------
// GEMM-T: C[p][m] = sum_k A[p][k] * B[m][k]; 64(p) x 128(m) tile, 4 waves (2x2),
// wave tile 32x64 = 2x4 frags of 16x16, K-chunk 64 (2 mfma k-steps).
// ONE barrier per step; B staged by global_load_lds (pre-swizzled source);
// A reg-staged with deferred select. XCD-pinned 1D grids (bid%8 = XCD).

// conv1x1: A = K^T (fp32->bf16 LDS transpose), B = w1b[br]. Writes raw bf16 f0b[br].
__global__ __launch_bounds__(256) void k_conv1T(const float* __restrict__ K,
                                                const unsigned short* __restrict__ w1b2,
                                                unsigned short* __restrict__ f0b2)
{
    __shared__ unsigned short As[2][64 * 64];
    __shared__ unsigned short Bs[2][128 * 64];
    int tid = threadIdx.x;
    int bid = blockIdx.x;
    int u = bid & 7;
    int t = bid >> 3;                // 0..71
    int bmi = u * 9 + t % 9;
    if (bmi >= 67) return;
    int combo = t / 9;               // 0..7
    int bm = bmi * 64;               // p tile
    int bn = (combo & 3) * 128;      // m tile
    int br = combo >> 2;
    const unsigned short* w1 = w1b2 + (size_t)br * 262144;
    unsigned short* f0 = f0b2 + (size_t)br * NP * 512;
    int lane = tid & 63;
    int w = tid >> 6;
    int wp = (w >> 1) * 32, wm = (w & 1) * 64;
    int ct = tid >> 4, p4 = (tid & 15) * 4;   // A staging map

    bool okj[4];
    int colj[4];
    #pragma unroll
    for (int j = 0; j < 4; j++) {
        okj[j] = (bm + p4 + j) < NP;
        colj[j] = okj[j] ? (p4 + j) : (NP - 1 - bm);
    }

    f32x4 acc[2][4];
    #pragma unroll
    for (int i = 0; i < 2; i++)
        #pragma unroll
        for (int j = 0; j < 4; j++) acc[i][j] = (f32x4){0.f, 0.f, 0.f, 0.f};

    float aE[16], aO[16];

    auto loadA = [&](int kc, float (&ar)[16]) {
        int c0 = kc * 64;
        #pragma unroll
        for (int pass = 0; pass < 4; pass++) {
            int cl = pass * 16 + ct;
            const float* src = K + (size_t)(c0 + cl) * NP + bm;
            #pragma unroll
            for (int j = 0; j < 4; j++) ar[pass * 4 + j] = src[colj[j]];
        }
    };
    auto writeA = [&](int buf, float (&ar)[16]) {
        #pragma unroll
        for (int pass = 0; pass < 4; pass++) {
            int cl = pass * 16 + ct;
            #pragma unroll
            for (int j = 0; j < 4; j++) {
                int row = p4 + j;
                int byte = (row * 128 + cl * 2) ^ ((row & 7) << 4);
                float v = okj[j] ? ar[pass * 4 + j] : 0.f;
                *(unsigned short*)((char*)As[buf] + byte) = f2bf(v);
            }
        }
    };
    auto stageB = [&](int kc, int buf) {
        const unsigned short* gb = w1 + (size_t)kc * 64 + (lane & 7) * 8;
        #pragma unroll
        for (int j = 0; j < 4; j++) {
            int row = (w * 4 + j) * 8 + (lane >> 3);
            gl_lds16(gb + (size_t)(bn + row) * 512,
                     (char*)Bs[buf] + (w * 4 + j) * 1024);
        }
    };
    auto mfmaStep = [&](int buf) {
        __builtin_amdgcn_s_setprio(1);
        #pragma unroll
        for (int ks = 0; ks < 2; ks++) {
            short8 af[2], bfr[4];
            #pragma unroll
            for (int fi = 0; fi < 2; fi++) {
                int row = wp + fi * 16 + (lane & 15);
                int byte = row * 128 + ((ks * 64 + ((lane >> 4) * 16)) ^ ((row & 7) << 4));
                af[fi] = *(const short8*)((char*)As[buf] + byte);
            }
            #pragma unroll
            for (int fj = 0; fj < 4; fj++) {
                int n = wm + fj * 16 + (lane & 15);
                int byte = n * 128 + ((ks * 64 + ((lane >> 4) * 16)) ^ ((n & 7) << 4));
                bfr[fj] = *(const short8*)((char*)Bs[buf] + byte);
            }
            #pragma unroll
            for (int fi = 0; fi < 2; fi++)
                #pragma unroll
                for (int fj = 0; fj < 4; fj++)
                    acc[fi][fj] = __builtin_amdgcn_mfma_f32_16x16x32_bf16(af[fi], bfr[fj], acc[fi][fj], 0, 0, 0);
        }
        __builtin_amdgcn_s_setprio(0);
    };

    loadA(0, aE);
    loadA(1, aO);
    stageB(0, 0);
    writeA(0, aE);
    __syncthreads();
    #pragma unroll
    for (int ib = 0; ib < 4; ib++) {
        int s0 = 2 * ib;
        if (s0 + 1 < 8) stageB(s0 + 1, 1);
        if (s0 + 2 < 8) loadA(s0 + 2, aE);
        mfmaStep(0);
        if (s0 + 1 < 8) writeA(1, aO);
        __syncthreads();
        int s1 = s0 + 1;
        if (s1 + 1 < 8) stageB(s1 + 1, 0);
        if (s1 + 2 < 8) loadA(s1 + 2, aO);
        mfmaStep(1);
        if (s1 + 1 < 8) writeA(0, aE);
        __syncthreads();
    }
    #pragma unroll
    for (int fi = 0; fi < 2; fi++)
        #pragma unroll
        for (int r = 0; r < 4; r++) {
            int p = bm + wp + fi * 16 + (lane >> 4) * 4 + r;
            if (p >= NP) continue;
            #pragma unroll
            for (int fj = 0; fj < 4; fj++) {
                int m = bn + wm + fj * 16 + (lane & 15);
                f0[(size_t)p * 512 + m] = f2bf(acc[fi][fj][r]);
            }
        }
}

// conv3x3 + residual + relu + fused conv8 partial (atomicAdd into pre-zeroed F2).
// Loop order: kc outer, tap inner (A halo stays cache-resident per kc).
__global__ __launch_bounds__(256) void k_conv3T(const unsigned short* __restrict__ f0b2,
                                                const unsigned short* __restrict__ w2b2,
                                                const float* __restrict__ amp3,
                                                const float* __restrict__ pha3,
                                                float* __restrict__ F2)
{
    __shared__ unsigned short As[2][64 * 64];
    __shared__ unsigned short Bs[2][128 * 64];
    __shared__ float w3s[8 * 128];
    int tid = threadIdx.x;
    int bid = blockIdx.x;
    int u = bid & 7;
    int bmi = bid >> 3;
    if (bmi >= 67) return;
    int bm = bmi * 64;
    int bnq = u & 3;
    int bn = bnq * 128;
    int br = u >> 2;
    const unsigned short* f0 = f0b2 + (size_t)br * NP * 512;
    const unsigned short* w2 = w2b2 + (size_t)br * 512 * 4608;
    const float* w3 = br ? pha3 : amp3;
    for (int i = tid; i < 1024; i += 256) {
        int h = i >> 7, c = i & 127;
        w3s[i] = w3[h * 512 + bn + c];
    }
    int lane = tid & 63;
    int w = tid >> 6;
    int wp = (w >> 1) * 32, wm = (w & 1) * 64;
    int ra = tid >> 2, sa = tid & 3;   // A staging: row, 16-elem segment
    int pA = bm + ra;
    int py = pA / 65, px = pA - py * 65;

    f32x4 acc[2][4];
    #pragma unroll
    for (int i = 0; i < 2; i++)
        #pragma unroll
        for (int j = 0; j < 4; j++) acc[i][j] = (f32x4){0.f, 0.f, 0.f, 0.f};

    u32x4 aE0, aE1, aO0, aO1;
    bool vE, vO;

    auto loadA = [&](int s, u32x4& a0, u32x4& a1, bool& vv) {
        int kc = s / 9, tap = s - kc * 9;
        int ky = tap / 3 - 1, kx = tap % 3 - 1;
        int sy = py + ky, sx = px + kx;
        bool valid = (pA < NP) && sy >= 0 && sy < 65 && sx >= 0 && sx < 65;
        int srow = valid ? (pA + ky * 65 + kx) : 0;
        const unsigned short* arow = f0 + (size_t)srow * 512 + kc * 64 + sa * 16;
        a0 = *(const u32x4*)arow;
        a1 = *(const u32x4*)(arow + 8);
        vv = valid;
    };
    auto writeA = [&](int buf, u32x4 a0, u32x4 a1, bool vv) {
        u32x4 z = {0, 0, 0, 0};
        u32x4 w0 = vv ? relu8(a0) : z;
        u32x4 w1 = vv ? relu8(a1) : z;
        int ab = ra * 128 + sa * 32;
        int swz = (ra & 7) << 4;
        *(u32x4*)((char*)As[buf] + (ab ^ swz)) = w0;
        *(u32x4*)((char*)As[buf] + ((ab + 16) ^ swz)) = w1;
    };
    auto stageB = [&](int s, int buf) {
        int kc = s / 9, tap = s - kc * 9;
        const unsigned short* gb = w2 + (size_t)tap * 512 + kc * 64 + (lane & 7) * 8;
        #pragma unroll
        for (int j = 0; j < 4; j++) {
            int row = (w * 4 + j) * 8 + (lane >> 3);
            gl_lds16(gb + (size_t)(bn + row) * 4608,
                     (char*)Bs[buf] + (w * 4 + j) * 1024);
        }
    };
    auto mfmaStep = [&](int buf) {
        __builtin_amdgcn_s_setprio(1);
        #pragma unroll
        for (int ks = 0; ks < 2; ks++) {
            short8 af[2], bfr[4];
            #pragma unroll
            for (int fi = 0; fi < 2; fi++) {
                int row = wp + fi * 16 + (lane & 15);
                int byte = row * 128 + ((ks * 64 + ((lane >> 4) * 16)) ^ ((row & 7) << 4));
                af[fi] = *(const short8*)((char*)As[buf] + byte);
            }
            #pragma unroll
            for (int fj = 0; fj < 4; fj++) {
                int n = wm + fj * 16 + (lane & 15);
                int byte = n * 128 + ((ks * 64 + ((lane >> 4) * 16)) ^ ((n & 7) << 4));
                bfr[fj] = *(const short8*)((char*)Bs[buf] + byte);
            }
            #pragma unroll
            for (int fi = 0; fi < 2; fi++)
                #pragma unroll
                for (int fj = 0; fj < 4; fj++)
                    acc[fi][fj] = __builtin_amdgcn_mfma_f32_16x16x32_bf16(af[fi], bfr[fj], acc[fi][fj], 0, 0, 0);
        }
        __builtin_amdgcn_s_setprio(0);
    };

    loadA(0, aE0, aE1, vE);
    loadA(1, aO0, aO1, vO);
    stageB(0, 0);
    writeA(0, aE0, aE1, vE);
    __syncthreads();
    for (int ib = 0; ib < 36; ib++) {
        int s0 = 2 * ib;
        if (s0 + 1 < 72) stageB(s0 + 1, 1);
        if (s0 + 2 < 72) loadA(s0 + 2, aE0, aE1, vE);
        mfmaStep(0);
        if (s0 + 1 < 72) writeA(1, aO0, aO1, vO);
        __syncthreads();
        int s1 = s0 + 1;
        if (s1 + 1 < 72) stageB(s1 + 1, 0);
        if (s1 + 2 < 72) loadA(s1 + 2, aO0, aO1, vO);
        mfmaStep(1);
        if (s1 + 1 < 72) writeA(0, aE0, aE1, vE);
        __syncthreads();
    }
    // epilogue: v = relu(acc + residual) -> LDS (swizzled bf16 tile in Bs[0])
    #pragma unroll
    for (int fi = 0; fi < 2; fi++)
        #pragma unroll
        for (int r = 0; r < 4; r++) {
            int row = wp + fi * 16 + (lane >> 4) * 4 + r;
            int p = bm + row;
            #pragma unroll
            for (int fj = 0; fj < 4; fj++) {
                int mcol = wm + fj * 16 + (lane & 15);
                float v = 0.f;
                if (p < NP)
                    v = fmaxf(acc[fi][fj][r] + bf2f(f0[(size_t)p * 512 + bn + mcol]), 0.f);
                int byte = (row * 256 + mcol * 2) ^ ((row & 7) << 4);
                *(unsigned short*)((char*)Bs[0] + byte) = f2bf(v);
            }
        }
    __syncthreads();
    // fused conv8: partial F2 over this block's 128 channels -> atomicAdd into F2
    int pl = tid >> 2, qc = tid & 3;
    float a8[8] = {};
    #pragma unroll 4
    for (int jj = 0; jj < 16; jj++) {
        int c = qc * 32 + jj * 2;
        int byte = (pl * 256 + c * 2) ^ ((pl & 7) << 4);
        unsigned int uu = *(const unsigned int*)((char*)Bs[0] + byte);
        float v0 = bf2f((unsigned short)(uu & 0xFFFF));
        float v1 = bf2f((unsigned short)(uu >> 16));
        #pragma unroll
        for (int h = 0; h < 8; h++)
            a8[h] += w3s[h * 128 + c] * v0 + w3s[h * 128 + c + 1] * v1;
    }
    #pragma unroll
    for (int h = 0; h < 8; h++) {
        a8[h] += __shfl_xor(a8[h], 1);
        a8[h] += __shfl_xor(a8[h], 2);
    }
    int p = bm + pl;
    if (qc == 0 && p < NP) {
        #pragma unroll
        for (int h = 0; h < 8; h++)
            atomicAdd(&F2[(size_t)(br * 8 + h) * NP + p], a8[h]);
    }
}

// down-proj both branches: Fo[h][j] = sum_p relu(F2[br][h][p]) * Wd[j][p] + bd[j]
__global__ __launch_bounds__(256) void k_down(const float* __restrict__ F2,
                                              const float* __restrict__ Wd1,
                                              const float* __restrict__ bd1,
                                              const float* __restrict__ Wd2,
                                              const float* __restrict__ bd2,
                                              float* __restrict__ Fa,
                                              float* __restrict__ Fp)
{
    int wid = threadIdx.x >> 6, lane = threadIdx.x & 63;
    int j = blockIdx.x * 4 + wid;
    if (j >= PR) return;
    int br = blockIdx.y;
    const float* Wd = br ? Wd2 : Wd1;
    const float* bd = br ? bd2 : bd1;
    const float* F2b = F2 + (size_t)br * 8 * NP;
    float* Fo = br ? Fp : Fa;
    const float* wr = Wd + (size_t)j * NP;
    float acc[8] = {};
    for (int p = lane; p < NP; p += 64) {
        float wv = wr[p];
        #pragma unroll
        for (int h = 0; h < 8; h++) acc[h] += wv * fmaxf(F2b[h * NP + p], 0.f);
    }
    #pragma unroll
    for (int h = 0; h < 8; h++) {
        #pragma unroll
        for (int off = 32; off; off >>= 1) acc[h] += __shfl_down(acc[h], off);
    }
    if (lane == 0) {
        float b = bd[j];
        #pragma unroll
        for (int h = 0; h < 8; h++) Fo[h * PR + j] = acc[h] + b;
    }
}

// ---------------- FFT stages ----------------

// stage B+C fused: col-DFT (f64) + amp/phase modulation (LDS) + inverse col-DFT (f32)
__global__ __launch_bounds__(128) void k_fftBC(const float* __restrict__ TrG,
                                               const float* __restrict__ TiG,
                                               const float* __restrict__ Fa,
                                               const float* __restrict__ Fp,
                                               const double* __restrict__ ctd,
                                               const double* __restrict__ snd,
                                               const float* __restrict__ ctf,
                                               const float* __restrict__ stf,
                                               float* __restrict__ CrG, float* __restrict__ CiG)
{
    int v = blockIdx.x, h = blockIdx.y;
    int t = threadIdx.x;
    __shared__ float TrS[65], TiS[65];
    __shared__ float BrS[65], BiS[65];
    __shared__ double c65[65], s65[65];
    __shared__ float cf[65], sf[65];
    if (t < 65) {
        TrS[t] = TrG[(h * 65 + t) * 33 + v];
        TiS[t] = TiG[(h * 65 + t) * 33 + v];
        c65[t] = ctd[t]; s65[t] = snd[t];
        cf[t] = ctf[t]; sf[t] = stf[t];
    }
    __syncthreads();
    int uu = t;
    if (uu < 65) {
        double sr = 0.0, si = 0.0;
        for (int y = 0; y < 65; y++) {
            int m = (uu * y) % 65;
            double c = c65[m], s = s65[m];
            double tr = (double)TrS[y], ti = (double)TiS[y];
            sr += tr * c + ti * s;
            si += ti * c - tr * s;
        }
        float re = (float)sr, im = (float)si;
        float mag = sqrtf(re * re + im * im);
        float ang = atan2f(im, re);
        int o = uu * 33 + v;
        float amp = Fa[h * PR + o] * mag;
        float ph  = Fp[h * PR + o] * ang;
        float sn, cn;
        sincosf(ph, &sn, &cn);
        BrS[uu] = amp * cn;
        BiS[uu] = amp * sn;
    }
    __syncthreads();
    int y = t;
    if (y < 65) {
        float sr = 0.f, si = 0.f;
        for (int u2 = 0; u2 < 65; u2++) {
            int m = (u2 * y) % 65;
            float c = cf[m], s = sf[m];
            float ar = BrS[u2], ai = BiS[u2];
            sr += ar * c - ai * s;
            si += ai * c + ar * s;
        }
        CrG[(h * 65 + y) * 33 + v] = sr;
        CiG[(h * 65 + y) * 33 + v] = si;
    }
}

// stage D: irfft rows + fused per-h row-max (atomicMax, uint-encoded)
__global__ __launch_bounds__(128) void k_fftD(const float* __restrict__ CrG,
                                              const float* __restrict__ CiG,
                                              const float* __restrict__ ctf,
                                              const float* __restrict__ stf,
                                              float* __restrict__ A2,
                                              unsigned int* __restrict__ mxb)
{
    int y = blockIdx.x, h = blockIdx.y;
    int t = threadIdx.x;
    __shared__ float CrS[33], CiS[33];
    __shared__ float c65[65], s65[65];
    __shared__ float red[128];
    if (t < 33) {
        CrS[t] = CrG[(h * 65 + y) * 33 + t];
        CiS[t] = CiG[(h * 65 + y) * 33 + t];
    }
    if (t < 65) { c65[t] = ctf[t]; s65[t] = stf[t]; }
    __syncthreads();
    int x = t;
    float s = -3.0e38f;
    if (x < 65) {
        s = CrS[0];
        for (int v = 1; v < 33; v++) {
            int m = (v * x) % 65;
            s += 2.f * (CrS[v] * c65[m] - CiS[v] * s65[m]);
        }
        s *= (1.f / 4225.f);
        A2[h * NP + y * 65 + x] = s;
    }
    red[t] = s;
    __syncthreads();
    for (int st = 64; st; st >>= 1) {
        if (t < st) red[t] = fmaxf(red[t], red[t + st]);
        __syncthreads();
    }
    if (t == 0) atomicMax(&mxb[h], fenc(red[0]));
}

// softmax pass 2: unnormalized weights + per-h sum (atomicAdd into pre-zeroed sumb)
__global__ __launch_bounds__(256) void k_sm2(const float* __restrict__ A2,
                                             const unsigned int* __restrict__ mxb,
                                             float* __restrict__ Wsm,
                                             float* __restrict__ sumb)
{
    int h = blockIdx.y, t = threadIdx.x;
    int p = blockIdx.x * 256 + t;
    float mx = fdec(mxb[h]);
    float w = 0.f;
    if (p < NP) {
        w = expf(A2[h * NP + p] - mx);
        Wsm[h * NP + p] = w;
    }
    __shared__ float red[256];
    red[t] = w;
    __syncthreads();
    for (int st = 128; st; st >>= 1) {
        if (t < st) red[t] += red[t + st];
        __syncthreads();
    }
    if (t == 0) atomicAdd(&sumb[h], red[0]);
}

// t[h][c] += sum_{p in quarter} Wsm_unnorm[h][p] * K[c][p]   (grid (128,4), atomic)
__global__ __launch_bounds__(256) void k_t(const float* __restrict__ K,
                                           const float* __restrict__ Wsm,
                                           float* __restrict__ t)
{
    int wid = threadIdx.x >> 6, lane = threadIdx.x & 63;
    int c = blockIdx.x * 4 + wid;
    int yq = blockIdx.y;
    int p0 = yq * 1057;
    int p1 = p0 + 1057; if (p1 > NP) p1 = NP;
    float acc[8] = {};
    for (int p = p0 + lane; p < p1; p += 64) {
        float kv = K[(size_t)c * NP + p];
        #pragma unroll
        for (int h = 0; h < 8; h++) acc[h] += kv * Wsm[h * NP + p];
    }
    #pragma unroll
    for (int h = 0; h < 8; h++) {
        #pragma unroll
        for (int off = 32; off; off >>= 1) acc[h] += __shfl_down(acc[h], off);
    }
    if (lane == 0) {
        #pragma unroll
        for (int h = 0; h < 8; h++) atomicAdd(&t[h * 512 + c], acc[h]);
    }
}

// x[hd] = (sum_c t[h][c]*Wv[hd][c]) / sumb[h] + bv[hd]
__global__ __launch_bounds__(256) void k_x(const float* __restrict__ t,
                                           const float* __restrict__ sumb,
                                           const float* __restrict__ Wv,
                                           const float* __restrict__ bv,
                                           float* __restrict__ x)
{
    int wid = threadIdx.x >> 6, lane = threadIdx.x & 63;
    int hd = blockIdx.x * 4 + wid;
    int h = hd >> 9;
    float s = 0.f;
    for (int c = lane; c < 512; c += 64) s += t[h * 512 + c] * Wv[(size_t)hd * 512 + c];
    #pragma unroll
    for (int off = 32; off; off >>= 1) s += __shfl_down(s, off);
    if (lane == 0) x[hd] = s / sumb[h] + bv[hd];
}

__global__ __launch_bounds__(256) void k_out(const float* __restrict__ x,
                                             const float* __restrict__ Wo,
                                             const float* __restrict__ bo,
                                             float* __restrict__ out)
{
    int wid = threadIdx.x >> 6, lane = threadIdx.x & 63;
    int j = blockIdx.x * 4 + wid;
    float s = 0.f;
    for (int i = lane; i < 4096; i += 64) s += x[i] * Wo[(size_t)j * 4096 + i];
    #pragma unroll
    for (int off = 32; off; off >>= 1) s += __shfl_down(s, off);
    if (lane == 0) out[j] = s + bo[j];
}

extern "C" void kernel_launch(void* const* d_in, const int* in_sizes, int n_in,
                              void* d_out, int out_size, void* d_ws, size_t ws_size,
                              hipStream_t stream)
{
    (void)in_sizes; (void)n_in; (void)out_size; (void)ws_size;
    const float* Q    = (const float*)d_in[0];
    const float* K    = (const float*)d_in[1];
    const float* Wq   = (const float*)d_in[2];
    const float* bq   = (const float*)d_in[3];
    const float* Wk   = (const float*)d_in[4];
    const float* bk   = (const float*)d_in[5];
    const float* Wv   = (const float*)d_in[6];
    const float* bv   = (const float*)d_in[7];
    const float* Wo   = (const float*)d_in[8];
    const float* bo   = (const float*)d_in[9];
    const float* amp1 = (const float*)d_in[10];
    const float* amp2 = (const float*)d_in[11];
    const float* amp3 = (const float*)d_in[12];
    const float* pha1 = (const float*)d_in[13];
    const float* pha2 = (const float*)d_in[14];
    const float* pha3 = (const float*)d_in[15];
    const float* Wd1  = (const float*)d_in[16];
    const float* bd1  = (const float*)d_in[17];
    const float* Wd2  = (const float*)d_in[18];
    const float* bd2  = (const float*)d_in[19];
    float* out = (float*)d_out;

    char* w = (char*)d_ws;
    auto alloc = [&](size_t bytes) { char* p = w; w += (bytes + 255) & ~(size_t)255; return p; };
    float* qv   = (float*)alloc(4096 * 4);
    float* qkp  = (float*)alloc(16 * 8 * 512 * 4);
    unsigned short* w1b2 = (unsigned short*)alloc((size_t)2 * 512 * 512 * 2);
    unsigned short* w2b2 = (unsigned short*)alloc((size_t)2 * 512 * 4608 * 2);
    unsigned short* f0b2 = (unsigned short*)alloc((size_t)2 * NP * 512 * 2);
    // ---- zeroed region start (single memset) ----
    float* F2   = (float*)alloc((size_t)2 * 8 * NP * 4);
    unsigned int* mxb = (unsigned int*)alloc(8 * 4);
    float* sumb = (float*)alloc(8 * 4);
    float* tt   = (float*)alloc(4096 * 4);
    char* zend  = w;
    // ---- zeroed region end ----
    float* Fa   = (float*)alloc(8 * PR * 4);
    float* Fp   = (float*)alloc(8 * PR * 4);
    double* ctd = (double*)alloc(65 * 8);
    double* snd = (double*)alloc(65 * 8);
    float* ctf  = (float*)alloc(65 * 4);
    float* stf  = (float*)alloc(65 * 4);
    float* TrG  = (float*)alloc(8 * PR * 4);
    float* TiG  = (float*)alloc(8 * PR * 4);
    float* CrG  = (float*)alloc(8 * PR * 4);
    float* CiG  = (float*)alloc(8 * PR * 4);
    // Ap aliases w2b2 (Ap dead before k_wprep writes w2b2)
    float* Ap   = (float*)w2b2;
    // post-conv small buffers alias f0b2 (dead after k_conv3T)
    {
        char* s2 = (char*)f0b2;
        auto alias = [&](size_t bytes) { char* p = s2; s2 += (bytes + 255) & ~(size_t)255; return p; };
        float* A2  = (float*)alias(8 * NP * 4);
        float* wsm = (float*)alias(8 * NP * 4);
        float* xx  = (float*)alias(4096 * 4);

        // zero F2 + mxb + sumb + tt in one shot
        hipMemsetAsync(F2, 0, (size_t)(zend - (char*)F2), stream);

        // attention logits path (fused: q-projection inline, twiddles in one block)
        k_qk4<<<dim3(2, 8, 16), 256, 0, stream>>>(Q, Wq, bq, Wk, qv, qkp, ctd, snd, ctf, stf);
        k_alogits3<<<dim3(17, 32), 256, 0, stream>>>(qkp, K, Ap);
        k_ared_fftA<<<dim3(65, 8), 128, 0, stream>>>(Ap, qv, bk, ctd, snd, TrG, TiG);

        // weight prep (merged, pre-swizzled; overwrites Ap region — after ared_fftA)
        k_wprep<<<dim3(1024, 2, 2), 256, 0, stream>>>(amp1, pha1, amp2, pha2, w1b2, w2b2);

        // conv branches, XCD-pinned 1D grids, 1-barrier pipelined + gl_lds B
        k_conv1T<<<576, 256, 0, stream>>>(K, w1b2, f0b2);
        k_conv3T<<<536, 256, 0, stream>>>(f0b2, w2b2, amp3, pha3, F2);
        k_down<<<dim3(537, 2), 256, 0, stream>>>(F2, Wd1, bd1, Wd2, bd2, Fa, Fp);

        // FFT modulation + softmax + output (f0b2 region reused as scratch)
        k_fftBC<<<dim3(33, 8), 128, 0, stream>>>(TrG, TiG, Fa, Fp, ctd, snd, ctf, stf, CrG, CiG);
        k_fftD<<<dim3(65, 8), 128, 0, stream>>>(CrG, CiG, ctf, stf, A2, mxb);
        k_sm2<<<dim3(17, 8), 256, 0, stream>>>(A2, mxb, wsm, sumb);
        k_t<<<dim3(128, 4), 256, 0, stream>>>(K, wsm, tt);
        k_x<<<1024, 256, 0, stream>>>(tt, sumb, Wv, bv, xx);
        k_out<<<128, 256, 0, stream>>>(xx, Wo, bo, out);
    }
}

// Round 15
// 237.033 us; speedup vs baseline: 1.1302x; 1.0253x over previous
//
#include <hip/hip_runtime.h>
#include <hip/hip_bf16.h>

#define NP 4225      // 65*65 spatial positions
#define PR 2145      // 65*33 rfft bins

typedef __attribute__((ext_vector_type(8))) short short8;    // 8 bf16 (4 VGPRs)
typedef __attribute__((ext_vector_type(4))) float f32x4;
typedef __attribute__((ext_vector_type(4))) unsigned int u32x4;

__device__ inline float bf2f(unsigned short u) {
    union { unsigned int i; float f; } x; x.i = ((unsigned int)u) << 16; return x.f;
}
__device__ inline unsigned short f2bf(float f) {   // RNE
    union { float f; unsigned int i; } x; x.f = f;
    unsigned int r = x.i + 0x7fff + ((x.i >> 16) & 1);
    return (unsigned short)(r >> 16);
}
// relu on 8 packed bf16 (zero halves with sign bit set)
__device__ inline u32x4 relu8(u32x4 v) {
    #pragma unroll
    for (int i = 0; i < 4; i++) {
        unsigned int s = v[i] & 0x80008000u;
        v[i] &= ~((s >> 15) * 0xFFFFu);
    }
    return v;
}
// async global->LDS, 16B per lane; lds base must be wave-uniform
__device__ inline void gl_lds16(const void* g, void* l) {
    __builtin_amdgcn_global_load_lds(
        (const __attribute__((address_space(1))) unsigned int*)g,
        (__attribute__((address_space(3))) unsigned int*)l,
        16, 0, 0);
}
// monotone float->uint encoding for atomicMax (init 0 < enc(any finite float))
__device__ inline unsigned int fenc(float x) {
    unsigned int u = __float_as_uint(x);
    return (u & 0x80000000u) ? ~u : (u | 0x80000000u);
}
__device__ inline float fdec(unsigned int e) {
    return (e & 0x80000000u) ? __uint_as_float(e & 0x7FFFFFFFu) : __uint_as_float(~e);
}

// ---------------- fused projection kernels ----------------

// Computes q[h, dz*32+g] inline, writes qv (bx==0), then qkp partial GEMV.
// Block (1,0,0) also fills the twiddle tables.
__global__ __launch_bounds__(256) void k_qk4(const float* __restrict__ Q,
                                             const float* __restrict__ Wq,
                                             const float* __restrict__ bq,
                                             const float* __restrict__ Wk,
                                             float* __restrict__ qv,
                                             float* __restrict__ qkp,
                                             double* __restrict__ ctd, double* __restrict__ snd,
                                             float* __restrict__ ctf, float* __restrict__ stf)
{
    int bx = blockIdx.x, h = blockIdx.y, dz = blockIdx.z;
    int tid = threadIdx.x;
    if (bx == 1 && h == 0 && dz == 0 && tid < 65) {
        double ang = 6.283185307179586476925286766559 * (double)tid / 65.0;
        double cv = cos(ang), sv = sin(ang);
        ctd[tid] = cv; snd[tid] = sv;
        ctf[tid] = (float)cv; stf[tid] = (float)sv;
    }
    __shared__ float qs[32];
    int g = tid >> 3, l = tid & 7;
    int row = h * 512 + dz * 32 + g;
    float s = 0.f;
    for (int d = l; d < 512; d += 8) s += Q[d] * Wq[(size_t)row * 512 + d];
    s += __shfl_xor(s, 1);
    s += __shfl_xor(s, 2);
    s += __shfl_xor(s, 4);
    if (l == 0) qs[g] = s + bq[row];
    __syncthreads();
    if (bx == 0 && tid < 32) qv[h * 512 + dz * 32 + tid] = qs[tid];
    int c = bx * 256 + tid;
    float s2 = 0.f;
    #pragma unroll 8
    for (int d = 0; d < 32; d++)
        s2 += qs[d] * Wk[(size_t)(h * 512 + dz * 32 + d) * 512 + c];
    qkp[(dz * 8 + h) * 512 + c] = s2;
}

// Ap[cz][h][p] partials: sum over 16 c of qk[h,c]*K[c,p]
__global__ __launch_bounds__(256) void k_alogits3(const float* __restrict__ qkp,
                                                  const float* __restrict__ K,
                                                  float* __restrict__ Ap)
{
    __shared__ float sqk[8][16];
    int tid = threadIdx.x;
    int cz = blockIdx.y;
    if (tid < 128) {
        int hh = tid >> 4, cc = tid & 15;
        float s = 0.f;
        #pragma unroll
        for (int dz = 0; dz < 16; dz++) s += qkp[(dz * 8 + hh) * 512 + cz * 16 + cc];
        sqk[hh][cc] = s;
    }
    __syncthreads();
    int p = blockIdx.x * 256 + tid;
    bool ok = p < NP;
    float acc[8] = {};
    #pragma unroll
    for (int cc = 0; cc < 16; cc++) {
        float kv = ok ? K[(size_t)(cz * 16 + cc) * NP + p] : 0.f;
        #pragma unroll
        for (int h = 0; h < 8; h++) acc[h] += sqk[h][cc] * kv;
    }
    if (ok) {
        #pragma unroll
        for (int h = 0; h < 8; h++) Ap[(size_t)(cz * 8 + h) * NP + p] = acc[h];
    }
}

// Fused: A-row reduce (Ap partials + qb inline) + f64 row-DFT -> TrG/TiG.
__global__ __launch_bounds__(128) void k_ared_fftA(const float* __restrict__ Ap,
                                                   const float* __restrict__ qv,
                                                   const float* __restrict__ bk,
                                                   const double* __restrict__ ctd,
                                                   const double* __restrict__ snd,
                                                   float* __restrict__ TrG, float* __restrict__ TiG)
{
    int y = blockIdx.x, h = blockIdx.y;
    int t = threadIdx.x;
    __shared__ float rowA[65];
    __shared__ double c65[65], s65[65];
    __shared__ float qbred[128];
    float qp = 0.f;
    for (int d = t; d < 512; d += 128) qp += qv[h * 512 + d] * bk[h * 512 + d];
    qbred[t] = qp;
    __syncthreads();
    for (int s = 64; s; s >>= 1) {
        if (t < s) qbred[t] += qbred[t + s];
        __syncthreads();
    }
    float qbh = qbred[0];
    if (t < 65) { c65[t] = ctd[t]; s65[t] = snd[t]; }
    const float sc = 0.04419417382415922f;   // 1/sqrt(512)
    if (t < 65) {
        int p = y * 65 + t;
        float s = 0.f;
        #pragma unroll 8
        for (int cz = 0; cz < 32; cz++) s += Ap[(size_t)(cz * 8 + h) * NP + p];
        rowA[t] = (s + qbh) * sc;
    }
    __syncthreads();
    int v = t;
    if (v < 33) {
        double sr = 0.0, si = 0.0;
        for (int x = 0; x < 65; x++) {
            int m = (v * x) % 65;
            double a = (double)rowA[x];
            sr += a * c65[m];
            si -= a * s65[m];
        }
        TrG[(h * 65 + y) * 33 + v] = (float)sr;
        TiG[(h * 65 + y) * 33 + v] = (float)si;
    }
}

// ---------------- weight prep (merged; both branches; pre-swizzled) ----------------
// Within each 64-elem kc-chunk, element c goes to (c&63)^((m&7)<<3).
// Blocks (z==0,y==0) also zero the atomic-accumulator region (replaces memset).

__global__ __launch_bounds__(256) void k_wprep(const float* __restrict__ a1,
                                               const float* __restrict__ p1,
                                               const float* __restrict__ a2,
                                               const float* __restrict__ p2,
                                               unsigned short* __restrict__ w1b2,
                                               unsigned short* __restrict__ w2b2,
                                               float* __restrict__ zbase, int zwords)
{
    int i = blockIdx.x * 256 + threadIdx.x;   // < 262144, i = m*512 + c
    int br = blockIdx.y;
    int m = i >> 9, c = i & 511;
    int cs = (c & ~63) | ((c & 63) ^ ((m & 7) << 3));
    if (blockIdx.z == 0) {
        if (br == 0) {
            for (int z = i; z < zwords; z += 262144) zbase[z] = 0.f;
        }
        const float* src = br ? p1 : a1;
        w1b2[(size_t)br * 262144 + m * 512 + cs] = f2bf(src[i]);
    } else {
        const float* src = (br ? p2 : a2) + (size_t)i * 9;
        unsigned short* dst = w2b2 + (size_t)br * 512 * 4608;
        #pragma unroll
        for (int t = 0; t < 9; t++) dst[(size_t)m * 4608 + t * 512 + cs] = f2bf(src[t]);
    }
}

// ---------------- MFMA conv kernels (R8-proven structure, frozen) ----------------
// GEMM-T: C[p][m] = sum_k A[p][k] * B[m][k]; 64(p) x 128(m) tile, 4 waves (2x2),
// wave tile 32x64 = 2x4 frags of 16x16, K-chunk 64 (2 mfma k-steps).
// ONE barrier per step; B staged by global_load_lds (pre-swizzled source);
// A reg-staged with deferred select. XCD-pinned 1D grids (bid%8 = XCD).

// conv1x1: A = K^T (fp32->bf16 LDS transpose), B = w1b[br]. Writes raw bf16 f0b[br].
__global__ __launch_bounds__(256) void k_conv1T(const float* __restrict__ K,
                                                const unsigned short* __restrict__ w1b2,
                                                unsigned short* __restrict__ f0b2)
{
    __shared__ unsigned short As[2][64 * 64];
    __shared__ unsigned short Bs[2][128 * 64];
    int tid = threadIdx.x;
    int bid = blockIdx.x;
    int u = bid & 7;
    int t = bid >> 3;                // 0..71
    int bmi = u * 9 + t % 9;
    if (bmi >= 67) return;
    int combo = t / 9;               // 0..7
    int bm = bmi * 64;               // p tile
    int bn = (combo & 3) * 128;      // m tile
    int br = combo >> 2;
    const unsigned short* w1 = w1b2 + (size_t)br * 262144;
    unsigned short* f0 = f0b2 + (size_t)br * NP * 512;
    int lane = tid & 63;
    int w = tid >> 6;
    int wp = (w >> 1) * 32, wm = (w & 1) * 64;
    int ct = tid >> 4, p4 = (tid & 15) * 4;   // A staging map

    bool okj[4];
    int colj[4];
    #pragma unroll
    for (int j = 0; j < 4; j++) {
        okj[j] = (bm + p4 + j) < NP;
        colj[j] = okj[j] ? (p4 + j) : (NP - 1 - bm);
    }

    f32x4 acc[2][4];
    #pragma unroll
    for (int i = 0; i < 2; i++)
        #pragma unroll
        for (int j = 0; j < 4; j++) acc[i][j] = (f32x4){0.f, 0.f, 0.f, 0.f};

    float aE[16], aO[16];

    auto loadA = [&](int kc, float (&ar)[16]) {
        int c0 = kc * 64;
        #pragma unroll
        for (int pass = 0; pass < 4; pass++) {
            int cl = pass * 16 + ct;
            const float* src = K + (size_t)(c0 + cl) * NP + bm;
            #pragma unroll
            for (int j = 0; j < 4; j++) ar[pass * 4 + j] = src[colj[j]];
        }
    };
    auto writeA = [&](int buf, float (&ar)[16]) {
        #pragma unroll
        for (int pass = 0; pass < 4; pass++) {
            int cl = pass * 16 + ct;
            #pragma unroll
            for (int j = 0; j < 4; j++) {
                int row = p4 + j;
                int byte = (row * 128 + cl * 2) ^ ((row & 7) << 4);
                float v = okj[j] ? ar[pass * 4 + j] : 0.f;
                *(unsigned short*)((char*)As[buf] + byte) = f2bf(v);
            }
        }
    };
    auto stageB = [&](int kc, int buf) {
        const unsigned short* gb = w1 + (size_t)kc * 64 + (lane & 7) * 8;
        #pragma unroll
        for (int j = 0; j < 4; j++) {
            int row = (w * 4 + j) * 8 + (lane >> 3);
            gl_lds16(gb + (size_t)(bn + row) * 512,
                     (char*)Bs[buf] + (w * 4 + j) * 1024);
        }
    };
    auto mfmaStep = [&](int buf) {
        __builtin_amdgcn_s_setprio(1);
        #pragma unroll
        for (int ks = 0; ks < 2; ks++) {
            short8 af[2], bfr[4];
            #pragma unroll
            for (int fi = 0; fi < 2; fi++) {
                int row = wp + fi * 16 + (lane & 15);
                int byte = row * 128 + ((ks * 64 + ((lane >> 4) * 16)) ^ ((row & 7) << 4));
                af[fi] = *(const short8*)((char*)As[buf] + byte);
            }
            #pragma unroll
            for (int fj = 0; fj < 4; fj++) {
                int n = wm + fj * 16 + (lane & 15);
                int byte = n * 128 + ((ks * 64 + ((lane >> 4) * 16)) ^ ((n & 7) << 4));
                bfr[fj] = *(const short8*)((char*)Bs[buf] + byte);
            }
            #pragma unroll
            for (int fi = 0; fi < 2; fi++)
                #pragma unroll
                for (int fj = 0; fj < 4; fj++)
                    acc[fi][fj] = __builtin_amdgcn_mfma_f32_16x16x32_bf16(af[fi], bfr[fj], acc[fi][fj], 0, 0, 0);
        }
        __builtin_amdgcn_s_setprio(0);
    };

    loadA(0, aE);
    loadA(1, aO);
    stageB(0, 0);
    writeA(0, aE);
    __syncthreads();
    #pragma unroll
    for (int ib = 0; ib < 4; ib++) {
        int s0 = 2 * ib;
        if (s0 + 1 < 8) stageB(s0 + 1, 1);
        if (s0 + 2 < 8) loadA(s0 + 2, aE);
        mfmaStep(0);
        if (s0 + 1 < 8) writeA(1, aO);
        __syncthreads();
        int s1 = s0 + 1;
        if (s1 + 1 < 8) stageB(s1 + 1, 0);
        if (s1 + 2 < 8) loadA(s1 + 2, aO);
        mfmaStep(1);
        if (s1 + 1 < 8) writeA(0, aE);
        __syncthreads();
    }
    #pragma unroll
    for (int fi = 0; fi < 2; fi++)
        #pragma unroll
        for (int r = 0; r < 4; r++) {
            int p = bm + wp + fi * 16 + (lane >> 4) * 4 + r;
            if (p >= NP) continue;
            #pragma unroll
            for (int fj = 0; fj < 4; fj++) {
                int m = bn + wm + fj * 16 + (lane & 15);
                f0[(size_t)p * 512 + m] = f2bf(acc[fi][fj][r]);
            }
        }
}

// conv3x3 + residual + relu + fused conv8 partial (atomicAdd into pre-zeroed F2).
// Loop order: kc outer, tap inner (A halo stays cache-resident per kc).
__global__ __launch_bounds__(256) void k_conv3T(const unsigned short* __restrict__ f0b2,
                                                const unsigned short* __restrict__ w2b2,
                                                const float* __restrict__ amp3,
                                                const float* __restrict__ pha3,
                                                float* __restrict__ F2)
{
    __shared__ unsigned short As[2][64 * 64];
    __shared__ unsigned short Bs[2][128 * 64];
    __shared__ float w3s[8 * 128];
    int tid = threadIdx.x;
    int bid = blockIdx.x;
    int u = bid & 7;
    int bmi = bid >> 3;
    if (bmi >= 67) return;
    int bm = bmi * 64;
    int bnq = u & 3;
    int bn = bnq * 128;
    int br = u >> 2;
    const unsigned short* f0 = f0b2 + (size_t)br * NP * 512;
    const unsigned short* w2 = w2b2 + (size_t)br * 512 * 4608;
    const float* w3 = br ? pha3 : amp3;
    for (int i = tid; i < 1024; i += 256) {
        int h = i >> 7, c = i & 127;
        w3s[i] = w3[h * 512 + bn + c];
    }
    int lane = tid & 63;
    int w = tid >> 6;
    int wp = (w >> 1) * 32, wm = (w & 1) * 64;
    int ra = tid >> 2, sa = tid & 3;   // A staging: row, 16-elem segment
    int pA = bm + ra;
    int py = pA / 65, px = pA - py * 65;

    f32x4 acc[2][4];
    #pragma unroll
    for (int i = 0; i < 2; i++)
        #pragma unroll
        for (int j = 0; j < 4; j++) acc[i][j] = (f32x4){0.f, 0.f, 0.f, 0.f};

    u32x4 aE0, aE1, aO0, aO1;
    bool vE, vO;

    auto loadA = [&](int s, u32x4& a0, u32x4& a1, bool& vv) {
        int kc = s / 9, tap = s - kc * 9;
        int ky = tap / 3 - 1, kx = tap % 3 - 1;
        int sy = py + ky, sx = px + kx;
        bool valid = (pA < NP) && sy >= 0 && sy < 65 && sx >= 0 && sx < 65;
        int srow = valid ? (pA + ky * 65 + kx) : 0;
        const unsigned short* arow = f0 + (size_t)srow * 512 + kc * 64 + sa * 16;
        a0 = *(const u32x4*)arow;
        a1 = *(const u32x4*)(arow + 8);
        vv = valid;
    };
    auto writeA = [&](int buf, u32x4 a0, u32x4 a1, bool vv) {
        u32x4 z = {0, 0, 0, 0};
        u32x4 w0 = vv ? relu8(a0) : z;
        u32x4 w1 = vv ? relu8(a1) : z;
        int ab = ra * 128 + sa * 32;
        int swz = (ra & 7) << 4;
        *(u32x4*)((char*)As[buf] + (ab ^ swz)) = w0;
        *(u32x4*)((char*)As[buf] + ((ab + 16) ^ swz)) = w1;
    };
    auto stageB = [&](int s, int buf) {
        int kc = s / 9, tap = s - kc * 9;
        const unsigned short* gb = w2 + (size_t)tap * 512 + kc * 64 + (lane & 7) * 8;
        #pragma unroll
        for (int j = 0; j < 4; j++) {
            int row = (w * 4 + j) * 8 + (lane >> 3);
            gl_lds16(gb + (size_t)(bn + row) * 4608,
                     (char*)Bs[buf] + (w * 4 + j) * 1024);
        }
    };
    auto mfmaStep = [&](int buf) {
        __builtin_amdgcn_s_setprio(1);
        #pragma unroll
        for (int ks = 0; ks < 2; ks++) {
            short8 af[2], bfr[4];
            #pragma unroll
            for (int fi = 0; fi < 2; fi++) {
                int row = wp + fi * 16 + (lane & 15);
                int byte = row * 128 + ((ks * 64 + ((lane >> 4) * 16)) ^ ((row & 7) << 4));
                af[fi] = *(const short8*)((char*)As[buf] + byte);
            }
            #pragma unroll
            for (int fj = 0; fj < 4; fj++) {
                int n = wm + fj * 16 + (lane & 15);
                int byte = n * 128 + ((ks * 64 + ((lane >> 4) * 16)) ^ ((n & 7) << 4));
                bfr[fj] = *(const short8*)((char*)Bs[buf] + byte);
            }
            #pragma unroll
            for (int fi = 0; fi < 2; fi++)
                #pragma unroll
                for (int fj = 0; fj < 4; fj++)
                    acc[fi][fj] = __builtin_amdgcn_mfma_f32_16x16x32_bf16(af[fi], bfr[fj], acc[fi][fj], 0, 0, 0);
        }
        __builtin_amdgcn_s_setprio(0);
    };

    loadA(0, aE0, aE1, vE);
    loadA(1, aO0, aO1, vO);
    stageB(0, 0);
    writeA(0, aE0, aE1, vE);
    __syncthreads();
    for (int ib = 0; ib < 36; ib++) {
        int s0 = 2 * ib;
        if (s0 + 1 < 72) stageB(s0 + 1, 1);
        if (s0 + 2 < 72) loadA(s0 + 2, aE0, aE1, vE);
        mfmaStep(0);
        if (s0 + 1 < 72) writeA(1, aO0, aO1, vO);
        __syncthreads();
        int s1 = s0 + 1;
        if (s1 + 1 < 72) stageB(s1 + 1, 0);
        if (s1 + 2 < 72) loadA(s1 + 2, aO0, aO1, vO);
        mfmaStep(1);
        if (s1 + 1 < 72) writeA(0, aE0, aE1, vE);
        __syncthreads();
    }
    // epilogue: v = relu(acc + residual) -> LDS (swizzled bf16 tile in Bs[0])
    #pragma unroll
    for (int fi = 0; fi < 2; fi++)
        #pragma unroll
        for (int r = 0; r < 4; r++) {
            int row = wp + fi * 16 + (lane >> 4) * 4 + r;
            int p = bm + row;
            #pragma unroll
            for (int fj = 0; fj < 4; fj++) {
                int mcol = wm + fj * 16 + (lane & 15);
                float v = 0.f;
                if (p < NP)
                    v = fmaxf(acc[fi][fj][r] + bf2f(f0[(size_t)p * 512 + bn + mcol]), 0.f);
                int byte = (row * 256 + mcol * 2) ^ ((row & 7) << 4);
                *(unsigned short*)((char*)Bs[0] + byte) = f2bf(v);
            }
        }
    __syncthreads();
    // fused conv8: partial F2 over this block's 128 channels -> atomicAdd into F2
    int pl = tid >> 2, qc = tid & 3;
    float a8[8] = {};
    #pragma unroll 4
    for (int jj = 0; jj < 16; jj++) {
        int c = qc * 32 + jj * 2;
        int byte = (pl * 256 + c * 2) ^ ((pl & 7) << 4);
        unsigned int uu = *(const unsigned int*)((char*)Bs[0] + byte);
        float v0 = bf2f((unsigned short)(uu & 0xFFFF));
        float v1 = bf2f((unsigned short)(uu >> 16));
        #pragma unroll
        for (int h = 0; h < 8; h++)
            a8[h] += w3s[h * 128 + c] * v0 + w3s[h * 128 + c + 1] * v1;
    }
    #pragma unroll
    for (int h = 0; h < 8; h++) {
        a8[h] += __shfl_xor(a8[h], 1);
        a8[h] += __shfl_xor(a8[h], 2);
    }
    int p = bm + pl;
    if (qc == 0 && p < NP) {
        #pragma unroll
        for (int h = 0; h < 8; h++)
            atomicAdd(&F2[(size_t)(br * 8 + h) * NP + p], a8[h]);
    }
}

// down-proj both branches: Fo[h][j] = sum_p relu(F2[br][h][p]) * Wd[j][p] + bd[j]
__global__ __launch_bounds__(256) void k_down(const float* __restrict__ F2,
                                              const float* __restrict__ Wd1,
                                              const float* __restrict__ bd1,
                                              const float* __restrict__ Wd2,
                                              const float* __restrict__ bd2,
                                              float* __restrict__ Fa,
                                              float* __restrict__ Fp)
{
    int wid = threadIdx.x >> 6, lane = threadIdx.x & 63;
    int j = blockIdx.x * 4 + wid;
    if (j >= PR) return;
    int br = blockIdx.y;
    const float* Wd = br ? Wd2 : Wd1;
    const float* bd = br ? bd2 : bd1;
    const float* F2b = F2 + (size_t)br * 8 * NP;
    float* Fo = br ? Fp : Fa;
    const float* wr = Wd + (size_t)j * NP;
    float acc[8] = {};
    for (int p = lane; p < NP; p += 64) {
        float wv = wr[p];
        #pragma unroll
        for (int h = 0; h < 8; h++) acc[h] += wv * fmaxf(F2b[h * NP + p], 0.f);
    }
    #pragma unroll
    for (int h = 0; h < 8; h++) {
        #pragma unroll
        for (int off = 32; off; off >>= 1) acc[h] += __shfl_down(acc[h], off);
    }
    if (lane == 0) {
        float b = bd[j];
        #pragma unroll
        for (int h = 0; h < 8; h++) Fo[h * PR + j] = acc[h] + b;
    }
}

// ---------------- FFT stages ----------------

// stage B+C fused: col-DFT (f64) + amp/phase modulation (LDS) + inverse col-DFT (f32)
__global__ __launch_bounds__(128) void k_fftBC(const float* __restrict__ TrG,
                                               const float* __restrict__ TiG,
                                               const float* __restrict__ Fa,
                                               const float* __restrict__ Fp,
                                               const double* __restrict__ ctd,
                                               const double* __restrict__ snd,
                                               const float* __restrict__ ctf,
                                               const float* __restrict__ stf,
                                               float* __restrict__ CrG, float* __restrict__ CiG)
{
    int v = blockIdx.x, h = blockIdx.y;
    int t = threadIdx.x;
    __shared__ float TrS[65], TiS[65];
    __shared__ float BrS[65], BiS[65];
    __shared__ double c65[65], s65[65];
    __shared__ float cf[65], sf[65];
    if (t < 65) {
        TrS[t] = TrG[(h * 65 + t) * 33 + v];
        TiS[t] = TiG[(h * 65 + t) * 33 + v];
        c65[t] = ctd[t]; s65[t] = snd[t];
        cf[t] = ctf[t]; sf[t] = stf[t];
    }
    __syncthreads();
    int uu = t;
    if (uu < 65) {
        double sr = 0.0, si = 0.0;
        for (int y = 0; y < 65; y++) {
            int m = (uu * y) % 65;
            double c = c65[m], s = s65[m];
            double tr = (double)TrS[y], ti = (double)TiS[y];
            sr += tr * c + ti * s;
            si += ti * c - tr * s;
        }
        float re = (float)sr, im = (float)si;
        float mag = sqrtf(re * re + im * im);
        float ang = atan2f(im, re);
        int o = uu * 33 + v;
        float amp = Fa[h * PR + o] * mag;
        float ph  = Fp[h * PR + o] * ang;
        float sn, cn;
        sincosf(ph, &sn, &cn);
        BrS[uu] = amp * cn;
        BiS[uu] = amp * sn;
    }
    __syncthreads();
    int y = t;
    if (y < 65) {
        float sr = 0.f, si = 0.f;
        for (int u2 = 0; u2 < 65; u2++) {
            int m = (u2 * y) % 65;
            float c = cf[m], s = sf[m];
            float ar = BrS[u2], ai = BiS[u2];
            sr += ar * c - ai * s;
            si += ai * c + ar * s;
        }
        CrG[(h * 65 + y) * 33 + v] = sr;
        CiG[(h * 65 + y) * 33 + v] = si;
    }
}

// stage D: irfft rows + fused per-h row-max (atomicMax, uint-encoded)
__global__ __launch_bounds__(128) void k_fftD(const float* __restrict__ CrG,
                                              const float* __restrict__ CiG,
                                              const float* __restrict__ ctf,
                                              const float* __restrict__ stf,
                                              float* __restrict__ A2,
                                              unsigned int* __restrict__ mxb)
{
    int y = blockIdx.x, h = blockIdx.y;
    int t = threadIdx.x;
    __shared__ float CrS[33], CiS[33];
    __shared__ float c65[65], s65[65];
    __shared__ float red[128];
    if (t < 33) {
        CrS[t] = CrG[(h * 65 + y) * 33 + t];
        CiS[t] = CiG[(h * 65 + y) * 33 + t];
    }
    if (t < 65) { c65[t] = ctf[t]; s65[t] = stf[t]; }
    __syncthreads();
    int x = t;
    float s = -3.0e38f;
    if (x < 65) {
        s = CrS[0];
        for (int v = 1; v < 33; v++) {
            int m = (v * x) % 65;
            s += 2.f * (CrS[v] * c65[m] - CiS[v] * s65[m]);
        }
        s *= (1.f / 4225.f);
        A2[h * NP + y * 65 + x] = s;
    }
    red[t] = s;
    __syncthreads();
    for (int st = 64; st; st >>= 1) {
        if (t < st) red[t] = fmaxf(red[t], red[t + st]);
        __syncthreads();
    }
    if (t == 0) atomicMax(&mxb[h], fenc(red[0]));
}

// t[h][c] += sum_{p in quarter} exp(A2[h][p]-mx[h]) * K[c][p]   (grid (128,4), atomic)
// blocks with bx==0 (wid==0 wave) also accumulate the per-quarter softmax sums.
__global__ __launch_bounds__(256) void k_t(const float* __restrict__ K,
                                           const float* __restrict__ A2,
                                           const unsigned int* __restrict__ mxb,
                                           float* __restrict__ t,
                                           float* __restrict__ sumb)
{
    int wid = threadIdx.x >> 6, lane = threadIdx.x & 63;
    int c = blockIdx.x * 4 + wid;
    int yq = blockIdx.y;
    int p0 = yq * 1057;
    int p1 = p0 + 1057; if (p1 > NP) p1 = NP;
    float mx[8];
    #pragma unroll
    for (int h = 0; h < 8; h++) mx[h] = fdec(mxb[h]);
    bool doSum = (blockIdx.x == 0) && (wid == 0);
    float acc[8] = {};
    float ws[8] = {};
    for (int p = p0 + lane; p < p1; p += 64) {
        float kv = K[(size_t)c * NP + p];
        #pragma unroll
        for (int h = 0; h < 8; h++) {
            float w = expf(A2[h * NP + p] - mx[h]);
            acc[h] += kv * w;
            if (doSum) ws[h] += w;
        }
    }
    #pragma unroll
    for (int h = 0; h < 8; h++) {
        #pragma unroll
        for (int off = 32; off; off >>= 1) acc[h] += __shfl_down(acc[h], off);
    }
    if (lane == 0) {
        #pragma unroll
        for (int h = 0; h < 8; h++) atomicAdd(&t[h * 512 + c], acc[h]);
    }
    if (doSum) {
        #pragma unroll
        for (int h = 0; h < 8; h++) {
            #pragma unroll
            for (int off = 32; off; off >>= 1) ws[h] += __shfl_down(ws[h], off);
        }
        if (lane == 0) {
            #pragma unroll
            for (int h = 0; h < 8; h++) atomicAdd(&sumb[h], ws[h]);
        }
    }
}

// x[hd] = (sum_c t[h][c]*Wv[hd][c]) / sumb[h] + bv[hd]
__global__ __launch_bounds__(256) void k_x(const float* __restrict__ t,
                                           const float* __restrict__ sumb,
                                           const float* __restrict__ Wv,
                                           const float* __restrict__ bv,
                                           float* __restrict__ x)
{
    int wid = threadIdx.x >> 6, lane = threadIdx.x & 63;
    int hd = blockIdx.x * 4 + wid;
    int h = hd >> 9;
    float s = 0.f;
    for (int c = lane; c < 512; c += 64) s += t[h * 512 + c] * Wv[(size_t)hd * 512 + c];
    #pragma unroll
    for (int off = 32; off; off >>= 1) s += __shfl_down(s, off);
    if (lane == 0) x[hd] = s / sumb[h] + bv[hd];
}

__global__ __launch_bounds__(256) void k_out(const float* __restrict__ x,
                                             const float* __restrict__ Wo,
                                             const float* __restrict__ bo,
                                             float* __restrict__ out)
{
    int wid = threadIdx.x >> 6, lane = threadIdx.x & 63;
    int j = blockIdx.x * 4 + wid;
    float s = 0.f;
    for (int i = lane; i < 4096; i += 64) s += x[i] * Wo[(size_t)j * 4096 + i];
    #pragma unroll
    for (int off = 32; off; off >>= 1) s += __shfl_down(s, off);
    if (lane == 0) out[j] = s + bo[j];
}

extern "C" void kernel_launch(void* const* d_in, const int* in_sizes, int n_in,
                              void* d_out, int out_size, void* d_ws, size_t ws_size,
                              hipStream_t stream)
{
    (void)in_sizes; (void)n_in; (void)out_size; (void)ws_size;
    const float* Q    = (const float*)d_in[0];
    const float* K    = (const float*)d_in[1];
    const float* Wq   = (const float*)d_in[2];
    const float* bq   = (const float*)d_in[3];
    const float* Wk   = (const float*)d_in[4];
    const float* bk   = (const float*)d_in[5];
    const float* Wv   = (const float*)d_in[6];
    const float* bv   = (const float*)d_in[7];
    const float* Wo   = (const float*)d_in[8];
    const float* bo   = (const float*)d_in[9];
    const float* amp1 = (const float*)d_in[10];
    const float* amp2 = (const float*)d_in[11];
    const float* amp3 = (const float*)d_in[12];
    const float* pha1 = (const float*)d_in[13];
    const float* pha2 = (const float*)d_in[14];
    const float* pha3 = (const float*)d_in[15];
    const float* Wd1  = (const float*)d_in[16];
    const float* bd1  = (const float*)d_in[17];
    const float* Wd2  = (const float*)d_in[18];
    const float* bd2  = (const float*)d_in[19];
    float* out = (float*)d_out;

    char* w = (char*)d_ws;
    auto alloc = [&](size_t bytes) { char* p = w; w += (bytes + 255) & ~(size_t)255; return p; };
    float* qv   = (float*)alloc(4096 * 4);
    float* qkp  = (float*)alloc(16 * 8 * 512 * 4);
    unsigned short* w1b2 = (unsigned short*)alloc((size_t)2 * 512 * 512 * 2);
    unsigned short* w2b2 = (unsigned short*)alloc((size_t)2 * 512 * 4608 * 2);
    unsigned short* f0b2 = (unsigned short*)alloc((size_t)2 * NP * 512 * 2);
    // ---- zeroed region start (zero-filled inside k_wprep) ----
    float* F2   = (float*)alloc((size_t)2 * 8 * NP * 4);
    unsigned int* mxb = (unsigned int*)alloc(8 * 4);
    float* sumb = (float*)alloc(8 * 4);
    float* tt   = (float*)alloc(4096 * 4);
    char* zend  = w;
    // ---- zeroed region end ----
    float* Fa   = (float*)alloc(8 * PR * 4);
    float* Fp   = (float*)alloc(8 * PR * 4);
    double* ctd = (double*)alloc(65 * 8);
    double* snd = (double*)alloc(65 * 8);
    float* ctf  = (float*)alloc(65 * 4);
    float* stf  = (float*)alloc(65 * 4);
    float* TrG  = (float*)alloc(8 * PR * 4);
    float* TiG  = (float*)alloc(8 * PR * 4);
    float* CrG  = (float*)alloc(8 * PR * 4);
    float* CiG  = (float*)alloc(8 * PR * 4);
    // Ap aliases w2b2 (Ap dead before k_wprep writes w2b2)
    float* Ap   = (float*)w2b2;
    // post-conv small buffers alias f0b2 (dead after k_conv3T)
    {
        char* s2 = (char*)f0b2;
        auto alias = [&](size_t bytes) { char* p = s2; s2 += (bytes + 255) & ~(size_t)255; return p; };
        float* A2  = (float*)alias(8 * NP * 4);
        float* xx  = (float*)alias(4096 * 4);

        int zwords = (int)((zend - (char*)F2) / 4);

        // attention logits path (fused: q-projection inline, twiddles in one block)
        k_qk4<<<dim3(2, 8, 16), 256, 0, stream>>>(Q, Wq, bq, Wk, qv, qkp, ctd, snd, ctf, stf);
        k_alogits3<<<dim3(17, 32), 256, 0, stream>>>(qkp, K, Ap);
        k_ared_fftA<<<dim3(65, 8), 128, 0, stream>>>(Ap, qv, bk, ctd, snd, TrG, TiG);

        // weight prep (merged, pre-swizzled; also zeroes the atomic region;
        // overwrites Ap region — after ared_fftA)
        k_wprep<<<dim3(1024, 2, 2), 256, 0, stream>>>(amp1, pha1, amp2, pha2, w1b2, w2b2,
                                                      F2, zwords);

        // conv branches, XCD-pinned 1D grids, 1-barrier pipelined + gl_lds B
        k_conv1T<<<576, 256, 0, stream>>>(K, w1b2, f0b2);
        k_conv3T<<<536, 256, 0, stream>>>(f0b2, w2b2, amp3, pha3, F2);
        k_down<<<dim3(537, 2), 256, 0, stream>>>(F2, Wd1, bd1, Wd2, bd2, Fa, Fp);

        // FFT modulation + softmax + output (f0b2 region reused as scratch)
        k_fftBC<<<dim3(33, 8), 128, 0, stream>>>(TrG, TiG, Fa, Fp, ctd, snd, ctf, stf, CrG, CiG);
        k_fftD<<<dim3(65, 8), 128, 0, stream>>>(CrG, CiG, ctf, stf, A2, mxb);
        k_t<<<dim3(128, 4), 256, 0, stream>>>(K, A2, mxb, tt, sumb);
        k_x<<<1024, 256, 0, stream>>>(tt, sumb, Wv, bv, xx);
        k_out<<<128, 256, 0, stream>>>(xx, Wo, bo, out);
    }
}

// Round 16
// 208.901 us; speedup vs baseline: 1.2824x; 1.1347x over previous
//
#include <hip/hip_runtime.h>
#include <hip/hip_bf16.h>

#define NP 4225      // 65*65 spatial positions
#define PR 2145      // 65*33 rfft bins

typedef __attribute__((ext_vector_type(8))) short short8;    // 8 bf16 (4 VGPRs)
typedef __attribute__((ext_vector_type(4))) float f32x4;
typedef __attribute__((ext_vector_type(4))) unsigned int u32x4;

__device__ inline float bf2f(unsigned short u) {
    union { unsigned int i; float f; } x; x.i = ((unsigned int)u) << 16; return x.f;
}
__device__ inline unsigned short f2bf(float f) {   // RNE
    union { float f; unsigned int i; } x; x.f = f;
    unsigned int r = x.i + 0x7fff + ((x.i >> 16) & 1);
    return (unsigned short)(r >> 16);
}
// relu on 8 packed bf16 (zero halves with sign bit set)
__device__ inline u32x4 relu8(u32x4 v) {
    #pragma unroll
    for (int i = 0; i < 4; i++) {
        unsigned int s = v[i] & 0x80008000u;
        v[i] &= ~((s >> 15) * 0xFFFFu);
    }
    return v;
}
// async global->LDS, 16B per lane; lds base must be wave-uniform
__device__ inline void gl_lds16(const void* g, void* l) {
    __builtin_amdgcn_global_load_lds(
        (const __attribute__((address_space(1))) unsigned int*)g,
        (__attribute__((address_space(3))) unsigned int*)l,
        16, 0, 0);
}
// monotone float->uint encoding for atomicMax (init 0 < enc(any finite float))
__device__ inline unsigned int fenc(float x) {
    unsigned int u = __float_as_uint(x);
    return (u & 0x80000000u) ? ~u : (u | 0x80000000u);
}
__device__ inline float fdec(unsigned int e) {
    return (e & 0x80000000u) ? __uint_as_float(e & 0x7FFFFFFFu) : __uint_as_float(~e);
}

// ---------------- fused projection kernels ----------------

// Computes q[h, dz*32+g] inline (float4 Wq loads), writes qv (bx==0), then qkp GEMV.
// Block (1,0,0) also fills the twiddle tables.
__global__ __launch_bounds__(256) void k_qk4(const float* __restrict__ Q,
                                             const float* __restrict__ Wq,
                                             const float* __restrict__ bq,
                                             const float* __restrict__ Wk,
                                             float* __restrict__ qv,
                                             float* __restrict__ qkp,
                                             double* __restrict__ ctd, double* __restrict__ snd,
                                             float* __restrict__ ctf, float* __restrict__ stf)
{
    int bx = blockIdx.x, h = blockIdx.y, dz = blockIdx.z;
    int tid = threadIdx.x;
    if (bx == 1 && h == 0 && dz == 0 && tid < 65) {
        double ang = 6.283185307179586476925286766559 * (double)tid / 65.0;
        double cv = cos(ang), sv = sin(ang);
        ctd[tid] = cv; snd[tid] = sv;
        ctf[tid] = (float)cv; stf[tid] = (float)sv;
    }
    __shared__ float qs[32];
    int g = tid >> 3, l = tid & 7;
    int row = h * 512 + dz * 32 + g;
    const f32x4* wq4 = (const f32x4*)(Wq + (size_t)row * 512);
    const f32x4* q4  = (const f32x4*)Q;
    float s = 0.f;
    #pragma unroll 4
    for (int i = l; i < 128; i += 8) {
        f32x4 a = q4[i], b = wq4[i];
        s += a[0] * b[0] + a[1] * b[1] + a[2] * b[2] + a[3] * b[3];
    }
    s += __shfl_xor(s, 1);
    s += __shfl_xor(s, 2);
    s += __shfl_xor(s, 4);
    if (l == 0) qs[g] = s + bq[row];
    __syncthreads();
    if (bx == 0 && tid < 32) qv[h * 512 + dz * 32 + tid] = qs[tid];
    int c = bx * 256 + tid;
    float s2 = 0.f;
    #pragma unroll 8
    for (int d = 0; d < 32; d++)
        s2 += qs[d] * Wk[(size_t)(h * 512 + dz * 32 + d) * 512 + c];
    qkp[(dz * 8 + h) * 512 + c] = s2;
}

// Ap[cz][h][p] partials: sum over 16 c of qk[h,c]*K[c,p]
__global__ __launch_bounds__(256) void k_alogits3(const float* __restrict__ qkp,
                                                  const float* __restrict__ K,
                                                  float* __restrict__ Ap)
{
    __shared__ float sqk[8][16];
    int tid = threadIdx.x;
    int cz = blockIdx.y;
    if (tid < 128) {
        int hh = tid >> 4, cc = tid & 15;
        float s = 0.f;
        #pragma unroll
        for (int dz = 0; dz < 16; dz++) s += qkp[(dz * 8 + hh) * 512 + cz * 16 + cc];
        sqk[hh][cc] = s;
    }
    __syncthreads();
    int p = blockIdx.x * 256 + tid;
    bool ok = p < NP;
    float acc[8] = {};
    #pragma unroll
    for (int cc = 0; cc < 16; cc++) {
        float kv = ok ? K[(size_t)(cz * 16 + cc) * NP + p] : 0.f;
        #pragma unroll
        for (int h = 0; h < 8; h++) acc[h] += sqk[h][cc] * kv;
    }
    if (ok) {
        #pragma unroll
        for (int h = 0; h < 8; h++) Ap[(size_t)(cz * 8 + h) * NP + p] = acc[h];
    }
}

// Fused: A-row reduce (Ap partials + qb inline) + f64 row-DFT -> TrG/TiG.
__global__ __launch_bounds__(128) void k_ared_fftA(const float* __restrict__ Ap,
                                                   const float* __restrict__ qv,
                                                   const float* __restrict__ bk,
                                                   const double* __restrict__ ctd,
                                                   const double* __restrict__ snd,
                                                   float* __restrict__ TrG, float* __restrict__ TiG)
{
    int y = blockIdx.x, h = blockIdx.y;
    int t = threadIdx.x;
    __shared__ float rowA[65];
    __shared__ double c65[65], s65[65];
    __shared__ float qbred[128];
    float qp = 0.f;
    for (int d = t; d < 512; d += 128) qp += qv[h * 512 + d] * bk[h * 512 + d];
    qbred[t] = qp;
    __syncthreads();
    for (int s = 64; s; s >>= 1) {
        if (t < s) qbred[t] += qbred[t + s];
        __syncthreads();
    }
    float qbh = qbred[0];
    if (t < 65) { c65[t] = ctd[t]; s65[t] = snd[t]; }
    const float sc = 0.04419417382415922f;   // 1/sqrt(512)
    if (t < 65) {
        int p = y * 65 + t;
        float s = 0.f;
        #pragma unroll 8
        for (int cz = 0; cz < 32; cz++) s += Ap[(size_t)(cz * 8 + h) * NP + p];
        rowA[t] = (s + qbh) * sc;
    }
    __syncthreads();
    int v = t;
    if (v < 33) {
        double sr = 0.0, si = 0.0;
        for (int x = 0; x < 65; x++) {
            int m = (v * x) % 65;
            double a = (double)rowA[x];
            sr += a * c65[m];
            si -= a * s65[m];
        }
        TrG[(h * 65 + y) * 33 + v] = (float)sr;
        TiG[(h * 65 + y) * 33 + v] = (float)si;
    }
}

// ---------------- weight prep (merged; both branches; pre-swizzled) ----------------
// Within each 64-elem kc-chunk, element c goes to (c&63)^((m&7)<<3).
// Blocks (z==0,y==0) also zero the atomic-accumulator region (replaces memset).

__global__ __launch_bounds__(256) void k_wprep(const float* __restrict__ a1,
                                               const float* __restrict__ p1,
                                               const float* __restrict__ a2,
                                               const float* __restrict__ p2,
                                               unsigned short* __restrict__ w1b2,
                                               unsigned short* __restrict__ w2b2,
                                               float* __restrict__ zbase, int zwords)
{
    int i = blockIdx.x * 256 + threadIdx.x;   // < 262144, i = m*512 + c
    int br = blockIdx.y;
    int m = i >> 9, c = i & 511;
    int cs = (c & ~63) | ((c & 63) ^ ((m & 7) << 3));
    if (blockIdx.z == 0) {
        if (br == 0) {
            for (int z = i; z < zwords; z += 262144) zbase[z] = 0.f;
        }
        const float* src = br ? p1 : a1;
        w1b2[(size_t)br * 262144 + m * 512 + cs] = f2bf(src[i]);
    } else {
        const float* src = (br ? p2 : a2) + (size_t)i * 9;
        unsigned short* dst = w2b2 + (size_t)br * 512 * 4608;
        #pragma unroll
        for (int t = 0; t < 9; t++) dst[(size_t)m * 4608 + t * 512 + cs] = f2bf(src[t]);
    }
}

// ---------------- MFMA conv kernels (R8-proven structure, frozen) ----------------
// GEMM-T: C[p][m] = sum_k A[p][k] * B[m][k]; 64(p) x 128(m) tile, 4 waves (2x2),
// wave tile 32x64 = 2x4 frags of 16x16, K-chunk 64 (2 mfma k-steps).
// ONE barrier per step; B staged by global_load_lds (pre-swizzled source);
// A reg-staged with deferred select. XCD-pinned 1D grids (bid%8 = XCD).

// conv1x1: A = K^T (fp32->bf16 LDS transpose), B = w1b[br]. Writes raw bf16 f0b[br].
__global__ __launch_bounds__(256) void k_conv1T(const float* __restrict__ K,
                                                const unsigned short* __restrict__ w1b2,
                                                unsigned short* __restrict__ f0b2)
{
    __shared__ unsigned short As[2][64 * 64];
    __shared__ unsigned short Bs[2][128 * 64];
    int tid = threadIdx.x;
    int bid = blockIdx.x;
    int u = bid & 7;
    int t = bid >> 3;                // 0..71
    int bmi = u * 9 + t % 9;
    if (bmi >= 67) return;
    int combo = t / 9;               // 0..7
    int bm = bmi * 64;               // p tile
    int bn = (combo & 3) * 128;      // m tile
    int br = combo >> 2;
    const unsigned short* w1 = w1b2 + (size_t)br * 262144;
    unsigned short* f0 = f0b2 + (size_t)br * NP * 512;
    int lane = tid & 63;
    int w = tid >> 6;
    int wp = (w >> 1) * 32, wm = (w & 1) * 64;
    int ct = tid >> 4, p4 = (tid & 15) * 4;   // A staging map

    bool okj[4];
    int colj[4];
    #pragma unroll
    for (int j = 0; j < 4; j++) {
        okj[j] = (bm + p4 + j) < NP;
        colj[j] = okj[j] ? (p4 + j) : (NP - 1 - bm);
    }

    f32x4 acc[2][4];
    #pragma unroll
    for (int i = 0; i < 2; i++)
        #pragma unroll
        for (int j = 0; j < 4; j++) acc[i][j] = (f32x4){0.f, 0.f, 0.f, 0.f};

    float aE[16], aO[16];

    auto loadA = [&](int kc, float (&ar)[16]) {
        int c0 = kc * 64;
        #pragma unroll
        for (int pass = 0; pass < 4; pass++) {
            int cl = pass * 16 + ct;
            const float* src = K + (size_t)(c0 + cl) * NP + bm;
            #pragma unroll
            for (int j = 0; j < 4; j++) ar[pass * 4 + j] = src[colj[j]];
        }
    };
    auto writeA = [&](int buf, float (&ar)[16]) {
        #pragma unroll
        for (int pass = 0; pass < 4; pass++) {
            int cl = pass * 16 + ct;
            #pragma unroll
            for (int j = 0; j < 4; j++) {
                int row = p4 + j;
                int byte = (row * 128 + cl * 2) ^ ((row & 7) << 4);
                float v = okj[j] ? ar[pass * 4 + j] : 0.f;
                *(unsigned short*)((char*)As[buf] + byte) = f2bf(v);
            }
        }
    };
    auto stageB = [&](int kc, int buf) {
        const unsigned short* gb = w1 + (size_t)kc * 64 + (lane & 7) * 8;
        #pragma unroll
        for (int j = 0; j < 4; j++) {
            int row = (w * 4 + j) * 8 + (lane >> 3);
            gl_lds16(gb + (size_t)(bn + row) * 512,
                     (char*)Bs[buf] + (w * 4 + j) * 1024);
        }
    };
    auto mfmaStep = [&](int buf) {
        __builtin_amdgcn_s_setprio(1);
        #pragma unroll
        for (int ks = 0; ks < 2; ks++) {
            short8 af[2], bfr[4];
            #pragma unroll
            for (int fi = 0; fi < 2; fi++) {
                int row = wp + fi * 16 + (lane & 15);
                int byte = row * 128 + ((ks * 64 + ((lane >> 4) * 16)) ^ ((row & 7) << 4));
                af[fi] = *(const short8*)((char*)As[buf] + byte);
            }
            #pragma unroll
            for (int fj = 0; fj < 4; fj++) {
                int n = wm + fj * 16 + (lane & 15);
                int byte = n * 128 + ((ks * 64 + ((lane >> 4) * 16)) ^ ((n & 7) << 4));
                bfr[fj] = *(const short8*)((char*)Bs[buf] + byte);
            }
            #pragma unroll
            for (int fi = 0; fi < 2; fi++)
                #pragma unroll
                for (int fj = 0; fj < 4; fj++)
                    acc[fi][fj] = __builtin_amdgcn_mfma_f32_16x16x32_bf16(af[fi], bfr[fj], acc[fi][fj], 0, 0, 0);
        }
        __builtin_amdgcn_s_setprio(0);
    };

    loadA(0, aE);
    loadA(1, aO);
    stageB(0, 0);
    writeA(0, aE);
    __syncthreads();
    #pragma unroll
    for (int ib = 0; ib < 4; ib++) {
        int s0 = 2 * ib;
        if (s0 + 1 < 8) stageB(s0 + 1, 1);
        if (s0 + 2 < 8) loadA(s0 + 2, aE);
        mfmaStep(0);
        if (s0 + 1 < 8) writeA(1, aO);
        __syncthreads();
        int s1 = s0 + 1;
        if (s1 + 1 < 8) stageB(s1 + 1, 0);
        if (s1 + 2 < 8) loadA(s1 + 2, aO);
        mfmaStep(1);
        if (s1 + 1 < 8) writeA(0, aE);
        __syncthreads();
    }
    #pragma unroll
    for (int fi = 0; fi < 2; fi++)
        #pragma unroll
        for (int r = 0; r < 4; r++) {
            int p = bm + wp + fi * 16 + (lane >> 4) * 4 + r;
            if (p >= NP) continue;
            #pragma unroll
            for (int fj = 0; fj < 4; fj++) {
                int m = bn + wm + fj * 16 + (lane & 15);
                f0[(size_t)p * 512 + m] = f2bf(acc[fi][fj][r]);
            }
        }
}

// conv3x3 + residual + relu + fused conv8 partial (atomicAdd into pre-zeroed F2).
// Loop order: kc outer, tap inner (A halo stays cache-resident per kc).
__global__ __launch_bounds__(256) void k_conv3T(const unsigned short* __restrict__ f0b2,
                                                const unsigned short* __restrict__ w2b2,
                                                const float* __restrict__ amp3,
                                                const float* __restrict__ pha3,
                                                float* __restrict__ F2)
{
    __shared__ unsigned short As[2][64 * 64];
    __shared__ unsigned short Bs[2][128 * 64];
    __shared__ float w3s[8 * 128];
    int tid = threadIdx.x;
    int bid = blockIdx.x;
    int u = bid & 7;
    int bmi = bid >> 3;
    if (bmi >= 67) return;
    int bm = bmi * 64;
    int bnq = u & 3;
    int bn = bnq * 128;
    int br = u >> 2;
    const unsigned short* f0 = f0b2 + (size_t)br * NP * 512;
    const unsigned short* w2 = w2b2 + (size_t)br * 512 * 4608;
    const float* w3 = br ? pha3 : amp3;
    for (int i = tid; i < 1024; i += 256) {
        int h = i >> 7, c = i & 127;
        w3s[i] = w3[h * 512 + bn + c];
    }
    int lane = tid & 63;
    int w = tid >> 6;
    int wp = (w >> 1) * 32, wm = (w & 1) * 64;
    int ra = tid >> 2, sa = tid & 3;   // A staging: row, 16-elem segment
    int pA = bm + ra;
    int py = pA / 65, px = pA - py * 65;

    f32x4 acc[2][4];
    #pragma unroll
    for (int i = 0; i < 2; i++)
        #pragma unroll
        for (int j = 0; j < 4; j++) acc[i][j] = (f32x4){0.f, 0.f, 0.f, 0.f};

    u32x4 aE0, aE1, aO0, aO1;
    bool vE, vO;

    auto loadA = [&](int s, u32x4& a0, u32x4& a1, bool& vv) {
        int kc = s / 9, tap = s - kc * 9;
        int ky = tap / 3 - 1, kx = tap % 3 - 1;
        int sy = py + ky, sx = px + kx;
        bool valid = (pA < NP) && sy >= 0 && sy < 65 && sx >= 0 && sx < 65;
        int srow = valid ? (pA + ky * 65 + kx) : 0;
        const unsigned short* arow = f0 + (size_t)srow * 512 + kc * 64 + sa * 16;
        a0 = *(const u32x4*)arow;
        a1 = *(const u32x4*)(arow + 8);
        vv = valid;
    };
    auto writeA = [&](int buf, u32x4 a0, u32x4 a1, bool vv) {
        u32x4 z = {0, 0, 0, 0};
        u32x4 w0 = vv ? relu8(a0) : z;
        u32x4 w1 = vv ? relu8(a1) : z;
        int ab = ra * 128 + sa * 32;
        int swz = (ra & 7) << 4;
        *(u32x4*)((char*)As[buf] + (ab ^ swz)) = w0;
        *(u32x4*)((char*)As[buf] + ((ab + 16) ^ swz)) = w1;
    };
    auto stageB = [&](int s, int buf) {
        int kc = s / 9, tap = s - kc * 9;
        const unsigned short* gb = w2 + (size_t)tap * 512 + kc * 64 + (lane & 7) * 8;
        #pragma unroll
        for (int j = 0; j < 4; j++) {
            int row = (w * 4 + j) * 8 + (lane >> 3);
            gl_lds16(gb + (size_t)(bn + row) * 4608,
                     (char*)Bs[buf] + (w * 4 + j) * 1024);
        }
    };
    auto mfmaStep = [&](int buf) {
        __builtin_amdgcn_s_setprio(1);
        #pragma unroll
        for (int ks = 0; ks < 2; ks++) {
            short8 af[2], bfr[4];
            #pragma unroll
            for (int fi = 0; fi < 2; fi++) {
                int row = wp + fi * 16 + (lane & 15);
                int byte = row * 128 + ((ks * 64 + ((lane >> 4) * 16)) ^ ((row & 7) << 4));
                af[fi] = *(const short8*)((char*)As[buf] + byte);
            }
            #pragma unroll
            for (int fj = 0; fj < 4; fj++) {
                int n = wm + fj * 16 + (lane & 15);
                int byte = n * 128 + ((ks * 64 + ((lane >> 4) * 16)) ^ ((n & 7) << 4));
                bfr[fj] = *(const short8*)((char*)Bs[buf] + byte);
            }
            #pragma unroll
            for (int fi = 0; fi < 2; fi++)
                #pragma unroll
                for (int fj = 0; fj < 4; fj++)
                    acc[fi][fj] = __builtin_amdgcn_mfma_f32_16x16x32_bf16(af[fi], bfr[fj], acc[fi][fj], 0, 0, 0);
        }
        __builtin_amdgcn_s_setprio(0);
    };

    loadA(0, aE0, aE1, vE);
    loadA(1, aO0, aO1, vO);
    stageB(0, 0);
    writeA(0, aE0, aE1, vE);
    __syncthreads();
    for (int ib = 0; ib < 36; ib++) {
        int s0 = 2 * ib;
        if (s0 + 1 < 72) stageB(s0 + 1, 1);
        if (s0 + 2 < 72) loadA(s0 + 2, aE0, aE1, vE);
        mfmaStep(0);
        if (s0 + 1 < 72) writeA(1, aO0, aO1, vO);
        __syncthreads();
        int s1 = s0 + 1;
        if (s1 + 1 < 72) stageB(s1 + 1, 0);
        if (s1 + 2 < 72) loadA(s1 + 2, aO0, aO1, vO);
        mfmaStep(1);
        if (s1 + 1 < 72) writeA(0, aE0, aE1, vE);
        __syncthreads();
    }
    // epilogue: v = relu(acc + residual) -> LDS (swizzled bf16 tile in Bs[0])
    #pragma unroll
    for (int fi = 0; fi < 2; fi++)
        #pragma unroll
        for (int r = 0; r < 4; r++) {
            int row = wp + fi * 16 + (lane >> 4) * 4 + r;
            int p = bm + row;
            #pragma unroll
            for (int fj = 0; fj < 4; fj++) {
                int mcol = wm + fj * 16 + (lane & 15);
                float v = 0.f;
                if (p < NP)
                    v = fmaxf(acc[fi][fj][r] + bf2f(f0[(size_t)p * 512 + bn + mcol]), 0.f);
                int byte = (row * 256 + mcol * 2) ^ ((row & 7) << 4);
                *(unsigned short*)((char*)Bs[0] + byte) = f2bf(v);
            }
        }
    __syncthreads();
    // fused conv8: partial F2 over this block's 128 channels -> atomicAdd into F2
    int pl = tid >> 2, qc = tid & 3;
    float a8[8] = {};
    #pragma unroll 4
    for (int jj = 0; jj < 16; jj++) {
        int c = qc * 32 + jj * 2;
        int byte = (pl * 256 + c * 2) ^ ((pl & 7) << 4);
        unsigned int uu = *(const unsigned int*)((char*)Bs[0] + byte);
        float v0 = bf2f((unsigned short)(uu & 0xFFFF));
        float v1 = bf2f((unsigned short)(uu >> 16));
        #pragma unroll
        for (int h = 0; h < 8; h++)
            a8[h] += w3s[h * 128 + c] * v0 + w3s[h * 128 + c + 1] * v1;
    }
    #pragma unroll
    for (int h = 0; h < 8; h++) {
        a8[h] += __shfl_xor(a8[h], 1);
        a8[h] += __shfl_xor(a8[h], 2);
    }
    int p = bm + pl;
    if (qc == 0 && p < NP) {
        #pragma unroll
        for (int h = 0; h < 8; h++)
            atomicAdd(&F2[(size_t)(br * 8 + h) * NP + p], a8[h]);
    }
}

// down-proj both branches: Fo[h][j] = sum_p relu(F2[br][h][p]) * Wd[j][p] + bd[j]
// Wd row loads vectorized (peel to 16B alignment + f32x4 main + scalar tail).
__global__ __launch_bounds__(256) void k_down(const float* __restrict__ F2,
                                              const float* __restrict__ Wd1,
                                              const float* __restrict__ bd1,
                                              const float* __restrict__ Wd2,
                                              const float* __restrict__ bd2,
                                              float* __restrict__ Fa,
                                              float* __restrict__ Fp)
{
    int wid = threadIdx.x >> 6, lane = threadIdx.x & 63;
    int j = blockIdx.x * 4 + wid;
    if (j >= PR) return;
    int br = blockIdx.y;
    const float* Wd = br ? Wd2 : Wd1;
    const float* bd = br ? bd2 : bd1;
    const float* F2b = F2 + (size_t)br * 8 * NP;
    float* Fo = br ? Fp : Fa;
    const float* wr = Wd + (size_t)j * NP;
    float acc[8] = {};
    // alignment peel: wr byte address mod 16 -> number of leading scalars
    int a0 = (int)(((16u - ((unsigned)(size_t)wr & 15u)) >> 2) & 3u);
    for (int p = lane; p < a0; p += 64) {
        float wv = wr[p];
        #pragma unroll
        for (int h = 0; h < 8; h++) acc[h] += wv * fmaxf(F2b[h * NP + p], 0.f);
    }
    int nv = (NP - a0) >> 2;
    const f32x4* wv4 = (const f32x4*)(wr + a0);
    for (int i = lane; i < nv; i += 64) {
        f32x4 wq = wv4[i];
        int pb = a0 + i * 4;
        #pragma unroll
        for (int cpt = 0; cpt < 4; cpt++) {
            float wv = wq[cpt];
            int p = pb + cpt;
            #pragma unroll
            for (int h = 0; h < 8; h++) acc[h] += wv * fmaxf(F2b[h * NP + p], 0.f);
        }
    }
    for (int p = a0 + nv * 4 + lane; p < NP; p += 64) {
        float wv = wr[p];
        #pragma unroll
        for (int h = 0; h < 8; h++) acc[h] += wv * fmaxf(F2b[h * NP + p], 0.f);
    }
    #pragma unroll
    for (int h = 0; h < 8; h++) {
        #pragma unroll
        for (int off = 32; off; off >>= 1) acc[h] += __shfl_down(acc[h], off);
    }
    if (lane == 0) {
        float b = bd[j];
        #pragma unroll
        for (int h = 0; h < 8; h++) Fo[h * PR + j] = acc[h] + b;
    }
}

// ---------------- FFT stages ----------------

// stage B+C fused: col-DFT (f64) + amp/phase modulation (LDS) + inverse col-DFT (f32)
__global__ __launch_bounds__(128) void k_fftBC(const float* __restrict__ TrG,
                                               const float* __restrict__ TiG,
                                               const float* __restrict__ Fa,
                                               const float* __restrict__ Fp,
                                               const double* __restrict__ ctd,
                                               const double* __restrict__ snd,
                                               const float* __restrict__ ctf,
                                               const float* __restrict__ stf,
                                               float* __restrict__ CrG, float* __restrict__ CiG)
{
    int v = blockIdx.x, h = blockIdx.y;
    int t = threadIdx.x;
    __shared__ float TrS[65], TiS[65];
    __shared__ float BrS[65], BiS[65];
    __shared__ double c65[65], s65[65];
    __shared__ float cf[65], sf[65];
    if (t < 65) {
        TrS[t] = TrG[(h * 65 + t) * 33 + v];
        TiS[t] = TiG[(h * 65 + t) * 33 + v];
        c65[t] = ctd[t]; s65[t] = snd[t];
        cf[t] = ctf[t]; sf[t] = stf[t];
    }
    __syncthreads();
    int uu = t;
    if (uu < 65) {
        double sr = 0.0, si = 0.0;
        for (int y = 0; y < 65; y++) {
            int m = (uu * y) % 65;
            double c = c65[m], s = s65[m];
            double tr = (double)TrS[y], ti = (double)TiS[y];
            sr += tr * c + ti * s;
            si += ti * c - tr * s;
        }
        float re = (float)sr, im = (float)si;
        float mag = sqrtf(re * re + im * im);
        float ang = atan2f(im, re);
        int o = uu * 33 + v;
        float amp = Fa[h * PR + o] * mag;
        float ph  = Fp[h * PR + o] * ang;
        float sn, cn;
        sincosf(ph, &sn, &cn);
        BrS[uu] = amp * cn;
        BiS[uu] = amp * sn;
    }
    __syncthreads();
    int y = t;
    if (y < 65) {
        float sr = 0.f, si = 0.f;
        for (int u2 = 0; u2 < 65; u2++) {
            int m = (u2 * y) % 65;
            float c = cf[m], s = sf[m];
            float ar = BrS[u2], ai = BiS[u2];
            sr += ar * c - ai * s;
            si += ai * c + ar * s;
        }
        CrG[(h * 65 + y) * 33 + v] = sr;
        CiG[(h * 65 + y) * 33 + v] = si;
    }
}

// stage D: irfft rows + fused per-h row-max (atomicMax, uint-encoded)
__global__ __launch_bounds__(128) void k_fftD(const float* __restrict__ CrG,
                                              const float* __restrict__ CiG,
                                              const float* __restrict__ ctf,
                                              const float* __restrict__ stf,
                                              float* __restrict__ A2,
                                              unsigned int* __restrict__ mxb)
{
    int y = blockIdx.x, h = blockIdx.y;
    int t = threadIdx.x;
    __shared__ float CrS[33], CiS[33];
    __shared__ float c65[65], s65[65];
    __shared__ float red[128];
    if (t < 33) {
        CrS[t] = CrG[(h * 65 + y) * 33 + t];
        CiS[t] = CiG[(h * 65 + y) * 33 + t];
    }
    if (t < 65) { c65[t] = ctf[t]; s65[t] = stf[t]; }
    __syncthreads();
    int x = t;
    float s = -3.0e38f;
    if (x < 65) {
        s = CrS[0];
        for (int v = 1; v < 33; v++) {
            int m = (v * x) % 65;
            s += 2.f * (CrS[v] * c65[m] - CiS[v] * s65[m]);
        }
        s *= (1.f / 4225.f);
        A2[h * NP + y * 65 + x] = s;
    }
    red[t] = s;
    __syncthreads();
    for (int st = 64; st; st >>= 1) {
        if (t < st) red[t] = fmaxf(red[t], red[t + st]);
        __syncthreads();
    }
    if (t == 0) atomicMax(&mxb[h], fenc(red[0]));
}

// t[h][c] += sum_{p in quarter} exp(A2[h][p]-mx[h]) * K[c][p]   (grid (128,4), atomic)
// blocks with bx==0 (wid==0 wave) also accumulate the per-quarter softmax sums.
__global__ __launch_bounds__(256) void k_t(const float* __restrict__ K,
                                           const float* __restrict__ A2,
                                           const unsigned int* __restrict__ mxb,
                                           float* __restrict__ t,
                                           float* __restrict__ sumb)
{
    int wid = threadIdx.x >> 6, lane = threadIdx.x & 63;
    int c = blockIdx.x * 4 + wid;
    int yq = blockIdx.y;
    int p0 = yq * 1057;
    int p1 = p0 + 1057; if (p1 > NP) p1 = NP;
    float mx[8];
    #pragma unroll
    for (int h = 0; h < 8; h++) mx[h] = fdec(mxb[h]);
    bool doSum = (blockIdx.x == 0) && (wid == 0);
    float acc[8] = {};
    float ws[8] = {};
    for (int p = p0 + lane; p < p1; p += 64) {
        float kv = K[(size_t)c * NP + p];
        #pragma unroll
        for (int h = 0; h < 8; h++) {
            float w = expf(A2[h * NP + p] - mx[h]);
            acc[h] += kv * w;
            if (doSum) ws[h] += w;
        }
    }
    #pragma unroll
    for (int h = 0; h < 8; h++) {
        #pragma unroll
        for (int off = 32; off; off >>= 1) acc[h] += __shfl_down(acc[h], off);
    }
    if (lane == 0) {
        #pragma unroll
        for (int h = 0; h < 8; h++) atomicAdd(&t[h * 512 + c], acc[h]);
    }
    if (doSum) {
        #pragma unroll
        for (int h = 0; h < 8; h++) {
            #pragma unroll
            for (int off = 32; off; off >>= 1) ws[h] += __shfl_down(ws[h], off);
        }
        if (lane == 0) {
            #pragma unroll
            for (int h = 0; h < 8; h++) atomicAdd(&sumb[h], ws[h]);
        }
    }
}

// x[hd] = (sum_c t[h][c]*Wv[hd][c]) / sumb[h] + bv[hd]   (float4 Wv loads)
__global__ __launch_bounds__(256) void k_x(const float* __restrict__ t,
                                           const float* __restrict__ sumb,
                                           const float* __restrict__ Wv,
                                           const float* __restrict__ bv,
                                           float* __restrict__ x)
{
    int wid = threadIdx.x >> 6, lane = threadIdx.x & 63;
    int hd = blockIdx.x * 4 + wid;
    int h = hd >> 9;
    const f32x4* wv4 = (const f32x4*)(Wv + (size_t)hd * 512);
    const f32x4* t4  = (const f32x4*)(t + h * 512);
    float s = 0.f;
    #pragma unroll 2
    for (int i = lane; i < 128; i += 64) {
        f32x4 a = t4[i], b = wv4[i];
        s += a[0] * b[0] + a[1] * b[1] + a[2] * b[2] + a[3] * b[3];
    }
    #pragma unroll
    for (int off = 32; off; off >>= 1) s += __shfl_down(s, off);
    if (lane == 0) x[hd] = s / sumb[h] + bv[hd];
}

// out[j] = sum_i x[i]*Wo[j][i] + bo[j]   (float4 Wo loads)
__global__ __launch_bounds__(256) void k_out(const float* __restrict__ x,
                                             const float* __restrict__ Wo,
                                             const float* __restrict__ bo,
                                             float* __restrict__ out)
{
    int wid = threadIdx.x >> 6, lane = threadIdx.x & 63;
    int j = blockIdx.x * 4 + wid;
    const f32x4* wo4 = (const f32x4*)(Wo + (size_t)j * 4096);
    const f32x4* x4  = (const f32x4*)x;
    float s = 0.f;
    #pragma unroll 4
    for (int i = lane; i < 1024; i += 64) {
        f32x4 a = x4[i], b = wo4[i];
        s += a[0] * b[0] + a[1] * b[1] + a[2] * b[2] + a[3] * b[3];
    }
    #pragma unroll
    for (int off = 32; off; off >>= 1) s += __shfl_down(s, off);
    if (lane == 0) out[j] = s + bo[j];
}

extern "C" void kernel_launch(void* const* d_in, const int* in_sizes, int n_in,
                              void* d_out, int out_size, void* d_ws, size_t ws_size,
                              hipStream_t stream)
{
    (void)in_sizes; (void)n_in; (void)out_size; (void)ws_size;
    const float* Q    = (const float*)d_in[0];
    const float* K    = (const float*)d_in[1];
    const float* Wq   = (const float*)d_in[2];
    const float* bq   = (const float*)d_in[3];
    const float* Wk   = (const float*)d_in[4];
    const float* bk   = (const float*)d_in[5];
    const float* Wv   = (const float*)d_in[6];
    const float* bv   = (const float*)d_in[7];
    const float* Wo   = (const float*)d_in[8];
    const float* bo   = (const float*)d_in[9];
    const float* amp1 = (const float*)d_in[10];
    const float* amp2 = (const float*)d_in[11];
    const float* amp3 = (const float*)d_in[12];
    const float* pha1 = (const float*)d_in[13];
    const float* pha2 = (const float*)d_in[14];
    const float* pha3 = (const float*)d_in[15];
    const float* Wd1  = (const float*)d_in[16];
    const float* bd1  = (const float*)d_in[17];
    const float* Wd2  = (const float*)d_in[18];
    const float* bd2  = (const float*)d_in[19];
    float* out = (float*)d_out;

    char* w = (char*)d_ws;
    auto alloc = [&](size_t bytes) { char* p = w; w += (bytes + 255) & ~(size_t)255; return p; };
    float* qv   = (float*)alloc(4096 * 4);
    float* qkp  = (float*)alloc(16 * 8 * 512 * 4);
    unsigned short* w1b2 = (unsigned short*)alloc((size_t)2 * 512 * 512 * 2);
    unsigned short* w2b2 = (unsigned short*)alloc((size_t)2 * 512 * 4608 * 2);
    unsigned short* f0b2 = (unsigned short*)alloc((size_t)2 * NP * 512 * 2);
    // ---- zeroed region start (zero-filled inside k_wprep) ----
    float* F2   = (float*)alloc((size_t)2 * 8 * NP * 4);
    unsigned int* mxb = (unsigned int*)alloc(8 * 4);
    float* sumb = (float*)alloc(8 * 4);
    float* tt   = (float*)alloc(4096 * 4);
    char* zend  = w;
    // ---- zeroed region end ----
    float* Fa   = (float*)alloc(8 * PR * 4);
    float* Fp   = (float*)alloc(8 * PR * 4);
    double* ctd = (double*)alloc(65 * 8);
    double* snd = (double*)alloc(65 * 8);
    float* ctf  = (float*)alloc(65 * 4);
    float* stf  = (float*)alloc(65 * 4);
    float* TrG  = (float*)alloc(8 * PR * 4);
    float* TiG  = (float*)alloc(8 * PR * 4);
    float* CrG  = (float*)alloc(8 * PR * 4);
    float* CiG  = (float*)alloc(8 * PR * 4);
    // Ap aliases w2b2 (Ap dead before k_wprep writes w2b2)
    float* Ap   = (float*)w2b2;
    // post-conv small buffers alias f0b2 (dead after k_conv3T)
    {
        char* s2 = (char*)f0b2;
        auto alias = [&](size_t bytes) { char* p = s2; s2 += (bytes + 255) & ~(size_t)255; return p; };
        float* A2  = (float*)alias(8 * NP * 4);
        float* xx  = (float*)alias(4096 * 4);

        int zwords = (int)((zend - (char*)F2) / 4);

        // attention logits path (fused: q-projection inline, twiddles in one block)
        k_qk4<<<dim3(2, 8, 16), 256, 0, stream>>>(Q, Wq, bq, Wk, qv, qkp, ctd, snd, ctf, stf);
        k_alogits3<<<dim3(17, 32), 256, 0, stream>>>(qkp, K, Ap);
        k_ared_fftA<<<dim3(65, 8), 128, 0, stream>>>(Ap, qv, bk, ctd, snd, TrG, TiG);

        // weight prep (merged, pre-swizzled; also zeroes the atomic region;
        // overwrites Ap region — after ared_fftA)
        k_wprep<<<dim3(1024, 2, 2), 256, 0, stream>>>(amp1, pha1, amp2, pha2, w1b2, w2b2,
                                                      F2, zwords);

        // conv branches, XCD-pinned 1D grids, 1-barrier pipelined + gl_lds B
        k_conv1T<<<576, 256, 0, stream>>>(K, w1b2, f0b2);
        k_conv3T<<<536, 256, 0, stream>>>(f0b2, w2b2, amp3, pha3, F2);
        k_down<<<dim3(537, 2), 256, 0, stream>>>(F2, Wd1, bd1, Wd2, bd2, Fa, Fp);

        // FFT modulation + softmax + output (f0b2 region reused as scratch)
        k_fftBC<<<dim3(33, 8), 128, 0, stream>>>(TrG, TiG, Fa, Fp, ctd, snd, ctf, stf, CrG, CiG);
        k_fftD<<<dim3(65, 8), 128, 0, stream>>>(CrG, CiG, ctf, stf, A2, mxb);
        k_t<<<dim3(128, 4), 256, 0, stream>>>(K, A2, mxb, tt, sumb);
        k_x<<<1024, 256, 0, stream>>>(tt, sumb, Wv, bv, xx);
        k_out<<<128, 256, 0, stream>>>(xx, Wo, bo, out);
    }
}